// Round 2
// baseline (1986.014 us; speedup 1.0000x reference)
//
#include <hip/hip_runtime.h>
#include <stdint.h>
#include <stddef.h>

#define Bn    16
#define Nn    10000
#define En    320000
#define CIN   32
#define COUTn 64
#define CCn   96            // CIN + COUT
#define WROW  1536          // Bn * CCn  (bf16 elements per node row)
#define WROWU 768           // uints per node row (2 bf16 each)
#define MROWS 160000        // Nn * Bn

// ---------------- bf16 helpers (raw bit ops, OCP bf16) ----------------
__device__ __forceinline__ float bflo(unsigned int p) { return __uint_as_float(p << 16); }
__device__ __forceinline__ float bfhi(unsigned int p) { return __uint_as_float(p & 0xffff0000u); }
__device__ __forceinline__ float bf2f(unsigned short u) { return __uint_as_float(((unsigned int)u) << 16); }
__device__ __forceinline__ unsigned int f2bfbits(float f) {
  unsigned int x = __float_as_uint(f);
  return (x + 0x7fffu + ((x >> 16) & 1u)) >> 16;   // round-nearest-even
}
__device__ __forceinline__ unsigned int pack2(float lo, float hi) {
  return f2bfbits(lo) | (f2bfbits(hi) << 16);
}

// ---------------- edge_index dtype detection ----------------
// If data is int64 (values < 2^31), every odd int32 word is a zero high-word.
__global__ void detect_idx(const int* __restrict__ idx, int* __restrict__ flag) {
  if (threadIdx.x == 0 && blockIdx.x == 0) {
    int is64 = 1;
    for (int i = 1; i < 128; i += 2) {
      if (idx[i] != 0) { is64 = 0; break; }
    }
    flag[0] = is64;
  }
}

__device__ __forceinline__ int gidx(const int* __restrict__ p, int i, int is64) {
  return is64 ? p[2 * (long long)i] : p[i];
}

// ---------------- degree + CSR row counts ----------------
__global__ void deg_cnt_kernel(const int* __restrict__ idx, const float* __restrict__ w,
                               float* __restrict__ deg_f, float* __restrict__ deg_b,
                               int* __restrict__ cnt_f, int* __restrict__ cnt_b,
                               const int* __restrict__ flag) {
  int e = blockIdx.x * 256 + threadIdx.x;
  int is64 = flag[0];
  if (e < En) {
    int s = gidx(idx, e, is64);
    int d = gidx(idx, En + e, is64);
    float we = w[e];
    atomicAdd(&deg_f[s], we);   // segment_sum(w, src)
    atomicAdd(&deg_b[d], we);   // segment_sum(w, dst)
    atomicAdd(&cnt_f[d], 1);    // CSR_f rows = dst
    atomicAdd(&cnt_b[s], 1);    // CSR_b rows = src
  }
}

// ---------------- exclusive scan (one block per array) ----------------
__global__ void exscan_two(const int* __restrict__ cnt_f, const int* __restrict__ cnt_b,
                           int* __restrict__ rp_f, int* __restrict__ rp_b,
                           int* __restrict__ cur_f, int* __restrict__ cur_b, int n) {
  const int* cnt = (blockIdx.x == 0) ? cnt_f : cnt_b;
  int* rp  = (blockIdx.x == 0) ? rp_f  : rp_b;
  int* cur = (blockIdx.x == 0) ? cur_f : cur_b;
  __shared__ int sh[256];
  int t = threadIdx.x;
  int running = 0;
  for (int base = 0; base < n; base += 256) {
    int v = (base + t < n) ? cnt[base + t] : 0;
    sh[t] = v;
    __syncthreads();
    for (int off = 1; off < 256; off <<= 1) {
      int x = (t >= off) ? sh[t - off] : 0;
      __syncthreads();
      sh[t] += x;
      __syncthreads();
    }
    int excl = sh[t] - v;
    if (base + t < n) { rp[base + t] = running + excl; cur[base + t] = running + excl; }
    int total = sh[255];
    __syncthreads();
    running += total;
  }
  if (t == 0) rp[n] = running;
}

// ---------------- CSR fill (with normalized weights) ----------------
__global__ void fill_csr(const int* __restrict__ idx, const float* __restrict__ w,
                         const float* __restrict__ deg_f, const float* __restrict__ deg_b,
                         int* __restrict__ cur_f, int* __restrict__ cur_b,
                         int* __restrict__ col_f, float* __restrict__ wf,
                         int* __restrict__ col_b, float* __restrict__ wb,
                         const int* __restrict__ flag) {
  int e = blockIdx.x * 256 + threadIdx.x;
  int is64 = flag[0];
  if (e < En) {
    int s = gidx(idx, e, is64);
    int d = gidx(idx, En + e, is64);
    float we = w[e];
    int pf = atomicAdd(&cur_f[d], 1);   // forward: out[dst] += in[src] * w/deg_f[src]
    col_f[pf] = s;
    wf[pf] = we / deg_f[s];
    int pb = atomicAdd(&cur_b[s], 1);   // backward: out[src] += in[dst] * w/deg_b[dst]
    col_b[pb] = d;
    wb[pb] = we / deg_b[d];
  }
}

// ---------------- fold W0' = W0 - W3 - W4 (Chebyshev -x0 terms) ----------------
__global__ void fold_w0(const float* __restrict__ ru_p, const float* __restrict__ c_p,
                        float* __restrict__ wru, float* __restrict__ wc) {
  int i = blockIdx.x * 256 + threadIdx.x;
  if (i < 96 * 128) {
    int k = i / 128, c = i % 128;
    wru[i] = ru_p[(k * 5 + 0) * 128 + c] - ru_p[(k * 5 + 3) * 128 + c] - ru_p[(k * 5 + 4) * 128 + c];
  }
  if (i < 96 * 64) {
    int k = i / 64, c = i % 64;
    wc[i] = c_p[(k * 5 + 0) * 64 + c] - c_p[(k * 5 + 3) * 64 + c] - c_p[(k * 5 + 4) * 64 + c];
  }
}

// ---------------- X0 builders (bf16 out, 2 elems/thread) ----------------
__global__ void build_x0_ru(const float* __restrict__ x, const float* __restrict__ h,
                            unsigned int* __restrict__ X0) {
  long long p = (long long)blockIdx.x * 256 + threadIdx.x;  // uint index over Nn*768
  int node = (int)(p / WROWU);
  int rem = (int)(p % WROWU);
  int b = rem / 48;
  int ci = (rem % 48) * 2;
  float lo, hi;
  if (ci < CIN) {
    const float* s = x + ((size_t)b * Nn + node) * CIN + ci;
    lo = s[0]; hi = s[1];
  } else {
    const float* s = h + ((size_t)b * Nn + node) * COUTn + (ci - CIN);
    lo = s[0]; hi = s[1];
  }
  X0[p] = pack2(lo, hi);
}

__global__ void build_x0_c(const float* __restrict__ x, const float* __restrict__ h,
                           const unsigned int* __restrict__ RU, unsigned int* __restrict__ X0) {
  long long p = (long long)blockIdx.x * 256 + threadIdx.x;
  int node = (int)(p / WROWU);
  int rem = (int)(p % WROWU);
  int b = rem / 48;
  int ci = (rem % 48) * 2;
  float lo, hi;
  if (ci < CIN) {
    const float* s = x + ((size_t)b * Nn + node) * CIN + ci;
    lo = s[0]; hi = s[1];
  } else {
    int o = ci - CIN;
    unsigned int rp = RU[((size_t)node * Bn + b) * 64 + (o >> 1)];  // r in cols [0,64)
    const float* s = h + ((size_t)b * Nn + node) * COUTn + o;
    lo = bflo(rp) * s[0];
    hi = bfhi(rp) * s[1];
  }
  X0[p] = pack2(lo, hi);
}

// ---------------- propagate (bf16): out[row,:] = alpha * sum_j w[j]*in[col[j],:] ----------------
__launch_bounds__(256)
__global__ void propagate_bf(const unsigned int* __restrict__ in, unsigned int* __restrict__ out,
                             const int* __restrict__ rowptr, const int* __restrict__ col,
                             const float* __restrict__ w, float alpha) {
  __shared__ int scol[256];
  __shared__ float sw[256];
  int row = blockIdx.x;
  int t = threadIdx.x;
  float a0 = 0.f, a1 = 0.f, a2 = 0.f, a3 = 0.f, a4 = 0.f, a5 = 0.f;
  int jb = rowptr[row], je = rowptr[row + 1];
  for (int base = jb; base < je; base += 256) {
    int m = je - base; if (m > 256) m = 256;
    __syncthreads();
    if (t < m) { scol[t] = col[base + t]; sw[t] = w[base + t]; }
    __syncthreads();
    for (int j = 0; j < m; ++j) {
      const unsigned int* src = in + (size_t)scol[j] * WROWU + t;
      float wt = sw[j];
      unsigned int p0 = src[0], p1 = src[256], p2 = src[512];
      a0 += wt * bflo(p0); a1 += wt * bfhi(p0);
      a2 += wt * bflo(p1); a3 += wt * bfhi(p1);
      a4 += wt * bflo(p2); a5 += wt * bfhi(p2);
    }
  }
  unsigned int* o = out + (size_t)row * WROWU + t;
  o[0]   = pack2(alpha * a0, alpha * a1);
  o[256] = pack2(alpha * a2, alpha * a3);
  o[512] = pack2(alpha * a4, alpha * a5);
}

// ---------------- GEMM: C[row, n0+col] (+)= sum_k X[row,k] * P[k*prs + n0+col] ----------------
// X: bf16 (M x 96) as uint pairs. P: f32, row stride prs floats (pre-offset by host).
// mode 0: C = bias + acc ; mode 1: C += acc.  cbf16: C storage is bf16.
// out_bn: C addressed as (batch, node, col) with row = node*16 + batch.
__launch_bounds__(256)
__global__ void gemm_k96(const unsigned int* __restrict__ X2, const float* __restrict__ P,
                         int prs, const float* __restrict__ bias,
                         void* __restrict__ C, int ldc, int mode, int out_bn, int cbf16) {
  __shared__ float XsT[96][68];   // transposed X tile (k-major), padded
  __shared__ float Ps[96][64];

  int m0 = blockIdx.x * 64;
  int n0 = blockIdx.y * 64;
  int tid = threadIdx.x;
  int tx = tid % 16;
  int ty = tid / 16;

  // load X tile: 64 rows x 96 bf16 = 1536 uint2 chunks (4 bf16 each)
  {
    const uint2* Xt = (const uint2*)(X2 + (size_t)m0 * 48);
    #pragma unroll
    for (int it = 0; it < 6; ++it) {
      int q = tid + it * 256;     // uint2 index, 1536 total
      uint2 v = Xt[q];
      int g = q * 4;              // element index
      int r = g / 96;
      int k = g % 96;
      XsT[k + 0][r] = bflo(v.x);
      XsT[k + 1][r] = bfhi(v.x);
      XsT[k + 2][r] = bflo(v.y);
      XsT[k + 3][r] = bfhi(v.y);
    }
  }
  // load P tile: 96 rows x 64 cols f32
  {
    #pragma unroll
    for (int it = 0; it < 6; ++it) {
      int q = tid + it * 256;     // float4 index, 1536 total
      int kk = q / 16;
      int nn = (q % 16) * 4;
      float4 v = *(const float4*)(P + (size_t)kk * prs + n0 + nn);
      *(float4*)&Ps[kk][nn] = v;
    }
  }
  __syncthreads();

  float acc[4][4];
  #pragma unroll
  for (int i = 0; i < 4; ++i)
    #pragma unroll
    for (int j = 0; j < 4; ++j) acc[i][j] = 0.f;

  #pragma unroll 4
  for (int k = 0; k < 96; ++k) {
    float4 a = *(const float4*)&XsT[k][ty * 4];
    float4 b = *(const float4*)&Ps[k][tx * 4];
    acc[0][0] += a.x * b.x; acc[0][1] += a.x * b.y; acc[0][2] += a.x * b.z; acc[0][3] += a.x * b.w;
    acc[1][0] += a.y * b.x; acc[1][1] += a.y * b.y; acc[1][2] += a.y * b.z; acc[1][3] += a.y * b.w;
    acc[2][0] += a.z * b.x; acc[2][1] += a.z * b.y; acc[2][2] += a.z * b.z; acc[2][3] += a.z * b.w;
    acc[3][0] += a.w * b.x; acc[3][1] += a.w * b.y; acc[3][2] += a.w * b.z; acc[3][3] += a.w * b.w;
  }

  #pragma unroll
  for (int i = 0; i < 4; ++i) {
    int row = m0 + ty * 4 + i;
    #pragma unroll
    for (int j = 0; j < 4; ++j) {
      int cg = n0 + tx * 4 + j;
      size_t addr;
      if (out_bn) addr = ((size_t)((row & 15) * Nn + (row >> 4))) * ldc + cg;
      else        addr = (size_t)row * ldc + cg;
      if (cbf16) {
        unsigned short* Cp = (unsigned short*)C;
        float v = (mode == 0) ? (bias[cg] + acc[i][j]) : (bf2f(Cp[addr]) + acc[i][j]);
        Cp[addr] = (unsigned short)f2bfbits(v);
      } else {
        float* Cf = (float*)C;
        float v = (mode == 0) ? (bias[cg] + acc[i][j]) : (Cf[addr] + acc[i][j]);
        Cf[addr] = v;
      }
    }
  }
}

// ---------------- elementwise ----------------
__global__ void sigmoid_bf(unsigned int* __restrict__ RU, int n) {
  int i = blockIdx.x * 256 + threadIdx.x;
  if (i < n) {
    unsigned int p = RU[i];
    float a = 1.f / (1.f + expf(-bflo(p)));
    float b = 1.f / (1.f + expf(-bfhi(p)));
    RU[i] = pack2(a, b);
  }
}

// out[b,node,o] = u*h + (1-u)*tanh(tanh(c_pre)); c_pre accumulated in d_out (f32)
__global__ void final_kernel(const unsigned short* __restrict__ RU, const float* __restrict__ h,
                             float* __restrict__ out) {
  long long i = (long long)blockIdx.x * 256 + threadIdx.x;
  int o = (int)(i & 63);
  long long bn = i >> 6;
  int node = (int)(bn % Nn);
  int b = (int)(bn / Nn);
  float u = bf2f(RU[((size_t)node * Bn + b) * 128 + 64 + o]);
  float cp = out[i];
  float c = tanhf(tanhf(cp));
  out[i] = u * h[i] + (1.f - u) * c;
}

// ---------------- host ----------------
extern "C" void kernel_launch(void* const* d_in, const int* in_sizes, int n_in,
                              void* d_out, int out_size, void* d_ws, size_t ws_size,
                              hipStream_t stream) {
  const float* x   = (const float*)d_in[0];
  const float* h   = (const float*)d_in[1];
  const int*   idx = (const int*)d_in[2];
  const float* ew  = (const float*)d_in[3];
  const float* ru_param = (const float*)d_in[4];
  const float* ru_bias  = (const float*)d_in[5];
  const float* c_param  = (const float*)d_in[6];
  const float* c_bias   = (const float*)d_in[7];
  float* outp = (float*)d_out;
  (void)in_sizes; (void)n_in; (void)out_size; (void)ws_size;

  char* ws = (char*)d_ws;
  size_t off = 0;
  auto alloc = [&](size_t bytes) -> char* {
    char* p = ws + off;
    off += (bytes + 255) & ~(size_t)255;
    return p;
  };

  float* deg_f = (float*)alloc(40960);
  float* deg_b = (float*)alloc(40960);
  int*   cnt_f = (int*)alloc(40960);
  int*   cnt_b = (int*)alloc(40960);
  int*   rp_f  = (int*)alloc((Nn + 1) * sizeof(int));
  int*   rp_b  = (int*)alloc((Nn + 1) * sizeof(int));
  int*   cur_f = (int*)alloc(Nn * sizeof(int));
  int*   cur_b = (int*)alloc(Nn * sizeof(int));
  int*   flag  = (int*)alloc(256);
  int*   col_f = (int*)alloc(En * sizeof(int));
  float* wf    = (float*)alloc(En * sizeof(float));
  int*   col_b = (int*)alloc(En * sizeof(int));
  float* wb    = (float*)alloc(En * sizeof(float));
  float* wru0  = (float*)alloc(96 * 128 * sizeof(float));
  float* wc0   = (float*)alloc(96 * 64 * sizeof(float));
  unsigned int* A  = (unsigned int*)alloc((size_t)Nn * WROWU * 4);   // bf16 wide buf
  unsigned int* Bx = (unsigned int*)alloc((size_t)Nn * WROWU * 4);   // bf16 wide buf
  unsigned int* RU = (unsigned int*)alloc((size_t)MROWS * 64 * 4);   // bf16 (M x 128)
  // total ~108 MB

  hipMemsetAsync(ws, 0, 4 * 40960, stream);   // deg_f, deg_b, cnt_f, cnt_b

  detect_idx<<<1, 64, 0, stream>>>(idx, flag);
  deg_cnt_kernel<<<En / 256, 256, 0, stream>>>(idx, ew, deg_f, deg_b, cnt_f, cnt_b, flag);
  exscan_two<<<2, 256, 0, stream>>>(cnt_f, cnt_b, rp_f, rp_b, cur_f, cur_b, Nn);
  fill_csr<<<En / 256, 256, 0, stream>>>(idx, ew, deg_f, deg_b, cur_f, cur_b,
                                         col_f, wf, col_b, wb, flag);
  fold_w0<<<48, 256, 0, stream>>>(ru_param, c_param, wru0, wc0);

  const int gBuild = Nn * WROWU / 256;   // 30000
  dim3 g1(MROWS / 64, 2);                // conv1: 128 out cols
  dim3 g2(MROWS / 64, 1);                // conv2: 64 out cols

  // ===== conv1 (ru): input [x, h], accumulate into RU (bf16) =====
  build_x0_ru<<<gBuild, 256, 0, stream>>>(x, h, A);
  gemm_k96<<<g1, 256, 0, stream>>>(A, wru0, 128, ru_bias, RU, 128, 0, 0, 1);          // l=0 (folded)
  propagate_bf<<<Nn, 256, 0, stream>>>(A, Bx, rp_f, col_f, wf, 1.f);                  // x1f
  gemm_k96<<<g1, 256, 0, stream>>>(Bx, ru_param + 1 * 128, 640, ru_bias, RU, 128, 1, 0, 1);
  propagate_bf<<<Nn, 256, 0, stream>>>(Bx, A, rp_f, col_f, wf, 2.f);                  // 2*P_f x1f
  gemm_k96<<<g1, 256, 0, stream>>>(A, ru_param + 3 * 128, 640, ru_bias, RU, 128, 1, 0, 1);
  build_x0_ru<<<gBuild, 256, 0, stream>>>(x, h, A);                                   // rebuild x0
  propagate_bf<<<Nn, 256, 0, stream>>>(A, Bx, rp_b, col_b, wb, 1.f);                  // x1b
  gemm_k96<<<g1, 256, 0, stream>>>(Bx, ru_param + 2 * 128, 640, ru_bias, RU, 128, 1, 0, 1);
  propagate_bf<<<Nn, 256, 0, stream>>>(Bx, A, rp_b, col_b, wb, 2.f);                  // 2*P_b x1b
  gemm_k96<<<g1, 256, 0, stream>>>(A, ru_param + 4 * 128, 640, ru_bias, RU, 128, 1, 0, 1);
  sigmoid_bf<<<MROWS * 64 / 256, 256, 0, stream>>>(RU, MROWS * 64);

  // ===== conv2 (c): input [x, r*h], accumulate into d_out (f32, batch-major) =====
  build_x0_c<<<gBuild, 256, 0, stream>>>(x, h, RU, A);
  gemm_k96<<<g2, 256, 0, stream>>>(A, wc0, 64, c_bias, outp, 64, 0, 1, 0);            // l=0 (folded)
  propagate_bf<<<Nn, 256, 0, stream>>>(A, Bx, rp_f, col_f, wf, 1.f);
  gemm_k96<<<g2, 256, 0, stream>>>(Bx, c_param + 1 * 64, 320, c_bias, outp, 64, 1, 1, 0);
  propagate_bf<<<Nn, 256, 0, stream>>>(Bx, A, rp_f, col_f, wf, 2.f);
  gemm_k96<<<g2, 256, 0, stream>>>(A, c_param + 3 * 64, 320, c_bias, outp, 64, 1, 1, 0);
  build_x0_c<<<gBuild, 256, 0, stream>>>(x, h, RU, A);
  propagate_bf<<<Nn, 256, 0, stream>>>(A, Bx, rp_b, col_b, wb, 1.f);
  gemm_k96<<<g2, 256, 0, stream>>>(Bx, c_param + 2 * 64, 320, c_bias, outp, 64, 1, 1, 0);
  propagate_bf<<<Nn, 256, 0, stream>>>(Bx, A, rp_b, col_b, wb, 2.f);
  gemm_k96<<<g2, 256, 0, stream>>>(A, c_param + 4 * 64, 320, c_bias, outp, 64, 1, 1, 0);

  final_kernel<<<(int)((long long)Bn * Nn * COUTn / 256), 256, 0, stream>>>(
      (const unsigned short*)RU, h, outp);
}

// Round 3
// 1678.420 us; speedup vs baseline: 1.1833x; 1.1833x over previous
//
#include <hip/hip_runtime.h>
#include <stdint.h>
#include <stddef.h>

#define Bn    16
#define Nn    10000
#define En    320000
#define CIN   32
#define COUTn 64
#define CCn   96            // CIN + COUT
#define WROW  1536          // Bn * CCn  (bf16 elements per node row)
#define WROWU 768           // uints per node row (2 bf16 each)
#define RHU   512           // uints per node row for rh-only (64ch * 16b / 2)
#define MROWS 160000        // Nn * Bn

// ---------------- bf16 helpers ----------------
__device__ __forceinline__ float bflo(unsigned int p) { return __uint_as_float(p << 16); }
__device__ __forceinline__ float bfhi(unsigned int p) { return __uint_as_float(p & 0xffff0000u); }
__device__ __forceinline__ float bf2f(unsigned short u) { return __uint_as_float(((unsigned int)u) << 16); }
__device__ __forceinline__ unsigned int f2bfbits(float f) {
  unsigned int x = __float_as_uint(f);
  return (x + 0x7fffu + ((x >> 16) & 1u)) >> 16;   // round-nearest-even
}
__device__ __forceinline__ unsigned int pack2(float lo, float hi) {
  return f2bfbits(lo) | (f2bfbits(hi) << 16);
}

// ---------------- edge_index dtype detection ----------------
__global__ void detect_idx(const int* __restrict__ idx, int* __restrict__ flag) {
  if (threadIdx.x == 0 && blockIdx.x == 0) {
    int is64 = 1;
    for (int i = 1; i < 128; i += 2) {
      if (idx[i] != 0) { is64 = 0; break; }
    }
    flag[0] = is64;
  }
}

__device__ __forceinline__ int gidx(const int* __restrict__ p, int i, int is64) {
  return is64 ? p[2 * (long long)i] : p[i];
}

// ---------------- degree + CSR row counts ----------------
__global__ void deg_cnt_kernel(const int* __restrict__ idx, const float* __restrict__ w,
                               float* __restrict__ deg_f, float* __restrict__ deg_b,
                               int* __restrict__ cnt_f, int* __restrict__ cnt_b,
                               const int* __restrict__ flag) {
  int e = blockIdx.x * 256 + threadIdx.x;
  int is64 = flag[0];
  if (e < En) {
    int s = gidx(idx, e, is64);
    int d = gidx(idx, En + e, is64);
    float we = w[e];
    atomicAdd(&deg_f[s], we);
    atomicAdd(&deg_b[d], we);
    atomicAdd(&cnt_f[d], 1);
    atomicAdd(&cnt_b[s], 1);
  }
}

// ---------------- exclusive scan ----------------
__global__ void exscan_two(const int* __restrict__ cnt_f, const int* __restrict__ cnt_b,
                           int* __restrict__ rp_f, int* __restrict__ rp_b,
                           int* __restrict__ cur_f, int* __restrict__ cur_b, int n) {
  const int* cnt = (blockIdx.x == 0) ? cnt_f : cnt_b;
  int* rp  = (blockIdx.x == 0) ? rp_f  : rp_b;
  int* cur = (blockIdx.x == 0) ? cur_f : cur_b;
  __shared__ int sh[256];
  int t = threadIdx.x;
  int running = 0;
  for (int base = 0; base < n; base += 256) {
    int v = (base + t < n) ? cnt[base + t] : 0;
    sh[t] = v;
    __syncthreads();
    for (int off = 1; off < 256; off <<= 1) {
      int x = (t >= off) ? sh[t - off] : 0;
      __syncthreads();
      sh[t] += x;
      __syncthreads();
    }
    int excl = sh[t] - v;
    if (base + t < n) { rp[base + t] = running + excl; cur[base + t] = running + excl; }
    int total = sh[255];
    __syncthreads();
    running += total;
  }
  if (t == 0) rp[n] = running;
}

// ---------------- CSR fill ----------------
__global__ void fill_csr(const int* __restrict__ idx, const float* __restrict__ w,
                         const float* __restrict__ deg_f, const float* __restrict__ deg_b,
                         int* __restrict__ cur_f, int* __restrict__ cur_b,
                         int* __restrict__ col_f, float* __restrict__ wf,
                         int* __restrict__ col_b, float* __restrict__ wb,
                         const int* __restrict__ flag) {
  int e = blockIdx.x * 256 + threadIdx.x;
  int is64 = flag[0];
  if (e < En) {
    int s = gidx(idx, e, is64);
    int d = gidx(idx, En + e, is64);
    float we = w[e];
    int pf = atomicAdd(&cur_f[d], 1);
    col_f[pf] = s;
    wf[pf] = we / deg_f[s];
    int pb = atomicAdd(&cur_b[s], 1);
    col_b[pb] = d;
    wb[pb] = we / deg_b[d];
  }
}

// ---------------- fold W0' = W0 - W3 - W4 ----------------
__global__ void fold_w0(const float* __restrict__ ru_p, const float* __restrict__ c_p,
                        float* __restrict__ wru, float* __restrict__ wc) {
  int i = blockIdx.x * 256 + threadIdx.x;
  if (i < 96 * 128) {
    int k = i / 128, c = i % 128;
    wru[i] = ru_p[(k * 5 + 0) * 128 + c] - ru_p[(k * 5 + 3) * 128 + c] - ru_p[(k * 5 + 4) * 128 + c];
  }
  if (i < 96 * 64) {
    int k = i / 64, c = i % 64;
    wc[i] = c_p[(k * 5 + 0) * 64 + c] - c_p[(k * 5 + 3) * 64 + c] - c_p[(k * 5 + 4) * 64 + c];
  }
}

// ---------------- X0 builders ----------------
__global__ void build_x0_ru(const float* __restrict__ x, const float* __restrict__ h,
                            unsigned int* __restrict__ X0) {
  long long p = (long long)blockIdx.x * 256 + threadIdx.x;
  int node = (int)(p / WROWU);
  int rem = (int)(p % WROWU);
  int b = rem / 48;
  int ci = (rem % 48) * 2;
  float lo, hi;
  if (ci < CIN) {
    const float* s = x + ((size_t)b * Nn + node) * CIN + ci;
    lo = s[0]; hi = s[1];
  } else {
    const float* s = h + ((size_t)b * Nn + node) * COUTn + (ci - CIN);
    lo = s[0]; hi = s[1];
  }
  X0[p] = pack2(lo, hi);
}

// full-width [x, r*h] (non-reuse fallback)
__global__ void build_x0_c(const float* __restrict__ x, const float* __restrict__ h,
                           const unsigned int* __restrict__ RU, unsigned int* __restrict__ X0) {
  long long p = (long long)blockIdx.x * 256 + threadIdx.x;
  int node = (int)(p / WROWU);
  int rem = (int)(p % WROWU);
  int b = rem / 48;
  int ci = (rem % 48) * 2;
  float lo, hi;
  if (ci < CIN) {
    const float* s = x + ((size_t)b * Nn + node) * CIN + ci;
    lo = s[0]; hi = s[1];
  } else {
    int o = ci - CIN;
    unsigned int rp = RU[((size_t)node * Bn + b) * 64 + (o >> 1)];
    const float* s = h + ((size_t)b * Nn + node) * COUTn + o;
    lo = bflo(rp) * s[0];
    hi = bfhi(rp) * s[1];
  }
  X0[p] = pack2(lo, hi);
}

// rh-only buffer: rh[node*512 + b*32 + ou] = pack(r*h) for 2 channels (reuse path)
__global__ void build_rh(const float* __restrict__ h, const unsigned int* __restrict__ RU,
                         unsigned int* __restrict__ rh) {
  long long q = (long long)blockIdx.x * 256 + threadIdx.x;   // over Nn*512
  int node = (int)(q >> 9);
  int rem = (int)(q & 511);
  int b = rem >> 5;
  int ou = rem & 31;
  int o = ou * 2;
  unsigned int rp = RU[((size_t)node * Bn + b) * 64 + ou];
  const float* hs = h + ((size_t)b * Nn + node) * COUTn + o;
  rh[q] = pack2(bflo(rp) * hs[0], bfhi(rp) * hs[1]);
}

// xbf[node*256 + b*16 + cu] = pack(x) (reuse path, conv2 l=0 x-part)
__global__ void build_xbf(const float* __restrict__ x, unsigned int* __restrict__ xbf) {
  long long q = (long long)blockIdx.x * 256 + threadIdx.x;   // over Nn*256
  int node = (int)(q >> 8);
  int rem = (int)(q & 255);
  int b = rem >> 4;
  int ci = (rem & 15) * 2;
  const float* xs = x + ((size_t)b * Nn + node) * CIN + ci;
  xbf[q] = pack2(xs[0], xs[1]);
}

// ---------------- chunked propagate ----------------
// grid.x = nchunk*Nn, chunk-major (chunk = blockIdx.x / Nn) for phase locality.
// Each thread owns ONE uint (2 bf16) of the output row; unroll-4 over edges.
// xsave (nullable, rowU==768 only): saves x-part (ci<32) for conv2 reuse.
__launch_bounds__(256)
__global__ void propagate_ck(const unsigned int* __restrict__ in, unsigned int* __restrict__ out,
                             unsigned int* __restrict__ xsave,
                             const int* __restrict__ rowptr, const int* __restrict__ col,
                             const float* __restrict__ w, float alpha, int rowU) {
  __shared__ int scol[256];
  __shared__ float sw[256];
  int row = blockIdx.x % Nn;
  int chunk = blockIdx.x / Nn;
  int t = threadIdx.x;
  int uoff = chunk * 256 + t;
  float alo = 0.f, ahi = 0.f;
  int jb = rowptr[row], je = rowptr[row + 1];
  for (int base = jb; base < je; base += 256) {
    int m = je - base; if (m > 256) m = 256;
    __syncthreads();
    if (t < m) { scol[t] = col[base + t]; sw[t] = w[base + t]; }
    __syncthreads();
    int j = 0;
    for (; j + 4 <= m; j += 4) {
      unsigned int p0 = in[(size_t)scol[j + 0] * rowU + uoff];
      unsigned int p1 = in[(size_t)scol[j + 1] * rowU + uoff];
      unsigned int p2 = in[(size_t)scol[j + 2] * rowU + uoff];
      unsigned int p3 = in[(size_t)scol[j + 3] * rowU + uoff];
      float w0 = sw[j + 0], w1 = sw[j + 1], w2 = sw[j + 2], w3 = sw[j + 3];
      alo += w0 * bflo(p0); ahi += w0 * bfhi(p0);
      alo += w1 * bflo(p1); ahi += w1 * bfhi(p1);
      alo += w2 * bflo(p2); ahi += w2 * bfhi(p2);
      alo += w3 * bflo(p3); ahi += w3 * bfhi(p3);
    }
    for (; j < m; ++j) {
      unsigned int p0 = in[(size_t)scol[j] * rowU + uoff];
      float w0 = sw[j];
      alo += w0 * bflo(p0); ahi += w0 * bfhi(p0);
    }
  }
  unsigned int o = pack2(alpha * alo, alpha * ahi);
  out[(size_t)row * rowU + uoff] = o;
  if (xsave) {
    int b = uoff / 48;
    int r = uoff % 48;
    if (r < 16) xsave[(size_t)row * 256 + b * 16 + r] = o;
  }
}

// ---------------- GEMM: C[row, n0+col] op= sum_k X[row,k] * P[k*prs + n0+col] ----------------
// X sources: Xc (contiguous 96ch rows, bf16 uint2) OR split (Xp: x-part 32ch, Rh: rh-part 64ch).
// mode 0: C = bias + acc; 1: C += acc; 2: C = sigmoid(C + acc) [bf16, conv1 last];
// mode 3: fused GRU final [f32 out_bn, conv2 last].
__launch_bounds__(256)
__global__ void gemm_k96(const uint2* __restrict__ Xc, const uint2* __restrict__ Xp,
                         const uint2* __restrict__ Rh,
                         const float* __restrict__ P, int prs,
                         const float* __restrict__ bias,
                         void* __restrict__ C, int ldc, int mode, int out_bn, int cbf16,
                         const unsigned short* __restrict__ RUb, const float* __restrict__ hg) {
  __shared__ float XsT[96][68];
  __shared__ float Ps[96][64];

  int m0 = blockIdx.x * 64;
  int n0 = blockIdx.y * 64;
  int tid = threadIdx.x;
  int tx = tid % 16;
  int ty = tid / 16;

  if (Xc) {
    const uint2* Xt = Xc + (size_t)m0 * 24;     // 24 uint2 per 96ch row
    #pragma unroll
    for (int it = 0; it < 6; ++it) {
      int q = tid + it * 256;                   // 1536 uint2 total
      uint2 v = Xt[q];
      int g = q * 4;
      int r = g / 96;
      int k = g % 96;
      XsT[k + 0][r] = bflo(v.x);
      XsT[k + 1][r] = bfhi(v.x);
      XsT[k + 2][r] = bflo(v.y);
      XsT[k + 3][r] = bfhi(v.y);
    }
  } else {
    int nodeBase = m0 >> 4;
    #pragma unroll
    for (int it = 0; it < 6; ++it) {
      int q = tid + it * 256;
      int node_l = q / 384;
      int rq = q % 384;
      uint2 v; int b, ci0;
      if (rq < 128) {            // x-part: 128 uint2/node = 16b * 8
        b = rq >> 3; ci0 = (rq & 7) * 4;
        v = Xp[(size_t)(nodeBase + node_l) * 128 + rq];
      } else {                   // rh-part: 256 uint2/node = 16b * 16
        int rr = rq - 128;
        b = rr >> 4; ci0 = 32 + (rr & 15) * 4;
        v = Rh[(size_t)(nodeBase + node_l) * 256 + rr];
      }
      int r = node_l * 16 + b;
      XsT[ci0 + 0][r] = bflo(v.x);
      XsT[ci0 + 1][r] = bfhi(v.x);
      XsT[ci0 + 2][r] = bflo(v.y);
      XsT[ci0 + 3][r] = bfhi(v.y);
    }
  }
  {
    #pragma unroll
    for (int it = 0; it < 6; ++it) {
      int q = tid + it * 256;
      int kk = q / 16;
      int nn = (q % 16) * 4;
      float4 v = *(const float4*)(P + (size_t)kk * prs + n0 + nn);
      *(float4*)&Ps[kk][nn] = v;
    }
  }
  __syncthreads();

  float acc[4][4];
  #pragma unroll
  for (int i = 0; i < 4; ++i)
    #pragma unroll
    for (int j = 0; j < 4; ++j) acc[i][j] = 0.f;

  #pragma unroll 4
  for (int k = 0; k < 96; ++k) {
    float4 a = *(const float4*)&XsT[k][ty * 4];
    float4 b = *(const float4*)&Ps[k][tx * 4];
    acc[0][0] += a.x * b.x; acc[0][1] += a.x * b.y; acc[0][2] += a.x * b.z; acc[0][3] += a.x * b.w;
    acc[1][0] += a.y * b.x; acc[1][1] += a.y * b.y; acc[1][2] += a.y * b.z; acc[1][3] += a.y * b.w;
    acc[2][0] += a.z * b.x; acc[2][1] += a.z * b.y; acc[2][2] += a.z * b.z; acc[2][3] += a.z * b.w;
    acc[3][0] += a.w * b.x; acc[3][1] += a.w * b.y; acc[3][2] += a.w * b.z; acc[3][3] += a.w * b.w;
  }

  #pragma unroll
  for (int i = 0; i < 4; ++i) {
    int row = m0 + ty * 4 + i;
    #pragma unroll
    for (int j = 0; j < 4; ++j) {
      int cg = n0 + tx * 4 + j;
      if (mode == 3) {
        int node = row >> 4, b = row & 15;
        size_t oaddr = ((size_t)b * Nn + node) * 64 + cg;
        float* Cf = (float*)C;
        float cp = Cf[oaddr] + acc[i][j];
        float cc = tanhf(tanhf(cp));
        float u = bf2f(RUb[(size_t)row * 128 + 64 + cg]);
        Cf[oaddr] = u * hg[oaddr] + (1.f - u) * cc;
      } else if (mode == 2) {
        unsigned short* Cp = (unsigned short*)C;
        size_t addr = (size_t)row * ldc + cg;
        float v = bf2f(Cp[addr]) + acc[i][j];
        v = 1.f / (1.f + expf(-v));
        Cp[addr] = (unsigned short)f2bfbits(v);
      } else {
        size_t addr;
        if (out_bn) addr = ((size_t)((row & 15) * Nn + (row >> 4))) * ldc + cg;
        else        addr = (size_t)row * ldc + cg;
        if (cbf16) {
          unsigned short* Cp = (unsigned short*)C;
          float v = (mode == 0) ? (bias[cg] + acc[i][j]) : (bf2f(Cp[addr]) + acc[i][j]);
          Cp[addr] = (unsigned short)f2bfbits(v);
        } else {
          float* Cf = (float*)C;
          float v = (mode == 0) ? (bias[cg] + acc[i][j]) : (Cf[addr] + acc[i][j]);
          Cf[addr] = v;
        }
      }
    }
  }
}

// ---------------- host ----------------
extern "C" void kernel_launch(void* const* d_in, const int* in_sizes, int n_in,
                              void* d_out, int out_size, void* d_ws, size_t ws_size,
                              hipStream_t stream) {
  const float* x   = (const float*)d_in[0];
  const float* h   = (const float*)d_in[1];
  const int*   idx = (const int*)d_in[2];
  const float* ew  = (const float*)d_in[3];
  const float* ru_param = (const float*)d_in[4];
  const float* ru_bias  = (const float*)d_in[5];
  const float* c_param  = (const float*)d_in[6];
  const float* c_bias   = (const float*)d_in[7];
  float* outp = (float*)d_out;
  (void)in_sizes; (void)n_in; (void)out_size;

  char* ws = (char*)d_ws;
  size_t off = 0;
  auto alloc = [&](size_t bytes) -> char* {
    char* p = ws + off;
    off += (bytes + 255) & ~(size_t)255;
    return p;
  };

  float* deg_f = (float*)alloc(40960);
  float* deg_b = (float*)alloc(40960);
  int*   cnt_f = (int*)alloc(40960);
  int*   cnt_b = (int*)alloc(40960);
  int*   rp_f  = (int*)alloc((Nn + 1) * sizeof(int));
  int*   rp_b  = (int*)alloc((Nn + 1) * sizeof(int));
  int*   cur_f = (int*)alloc(Nn * sizeof(int));
  int*   cur_b = (int*)alloc(Nn * sizeof(int));
  int*   flag  = (int*)alloc(256);
  int*   col_f = (int*)alloc(En * sizeof(int));
  float* wf    = (float*)alloc(En * sizeof(float));
  int*   col_b = (int*)alloc(En * sizeof(int));
  float* wb    = (float*)alloc(En * sizeof(float));
  float* wru0  = (float*)alloc(96 * 128 * sizeof(float));
  float* wc0   = (float*)alloc(96 * 64 * sizeof(float));
  unsigned int* A  = (unsigned int*)alloc((size_t)Nn * WROWU * 4);   // wide bf16
  unsigned int* Bx = (unsigned int*)alloc((size_t)Nn * WROWU * 4);   // wide bf16
  unsigned int* RU = (unsigned int*)alloc((size_t)MROWS * 64 * 4);   // bf16 (M x 128)
  // base footprint ~108 MB

  bool reuse = ws_size >= (size_t)176 * 1024 * 1024;
  unsigned int *xs_f1 = nullptr, *xs_f2 = nullptr, *xs_b1 = nullptr, *xs_b2 = nullptr, *xbf = nullptr;
  unsigned int *rh0 = nullptr, *rhA = nullptr, *rhB = nullptr;
  if (reuse) {
    xs_f1 = (unsigned int*)alloc((size_t)Nn * 256 * 4);
    xs_f2 = (unsigned int*)alloc((size_t)Nn * 256 * 4);
    xs_b1 = (unsigned int*)alloc((size_t)Nn * 256 * 4);
    xs_b2 = (unsigned int*)alloc((size_t)Nn * 256 * 4);
    xbf   = (unsigned int*)alloc((size_t)Nn * 256 * 4);
    // rh buffers overlay conv1's A∪Bx (dead after conv1): 3 * Nn*512*4 = Nn*768*4*2 exactly
    rh0 = A;
    rhA = A + (size_t)Nn * RHU;
    rhB = A + (size_t)Nn * RHU * 2;
  }

  hipMemsetAsync(ws, 0, 4 * 40960, stream);

  detect_idx<<<1, 64, 0, stream>>>(idx, flag);
  deg_cnt_kernel<<<En / 256, 256, 0, stream>>>(idx, ew, deg_f, deg_b, cnt_f, cnt_b, flag);
  exscan_two<<<2, 256, 0, stream>>>(cnt_f, cnt_b, rp_f, rp_b, cur_f, cur_b, Nn);
  fill_csr<<<En / 256, 256, 0, stream>>>(idx, ew, deg_f, deg_b, cur_f, cur_b,
                                         col_f, wf, col_b, wb, flag);
  fold_w0<<<48, 256, 0, stream>>>(ru_param, c_param, wru0, wc0);

  const int gBuild = Nn * WROWU / 256;   // 30000
  dim3 g1(MROWS / 64, 2);
  dim3 g2(MROWS / 64, 1);
  const int gp1 = 3 * Nn;                // conv1 propagate grid (3 chunks)

  const unsigned short* RUs = (const unsigned short*)RU;

  // ===== conv1 (ru) =====
  build_x0_ru<<<gBuild, 256, 0, stream>>>(x, h, A);
  gemm_k96<<<g1, 256, 0, stream>>>((const uint2*)A, nullptr, nullptr, wru0, 128, ru_bias, RU, 128, 0, 0, 1, nullptr, nullptr);
  propagate_ck<<<gp1, 256, 0, stream>>>(A, Bx, xs_f1, rp_f, col_f, wf, 1.f, WROWU);
  gemm_k96<<<g1, 256, 0, stream>>>((const uint2*)Bx, nullptr, nullptr, ru_param + 1 * 128, 640, ru_bias, RU, 128, 1, 0, 1, nullptr, nullptr);
  propagate_ck<<<gp1, 256, 0, stream>>>(Bx, A, xs_f2, rp_f, col_f, wf, 2.f, WROWU);
  gemm_k96<<<g1, 256, 0, stream>>>((const uint2*)A, nullptr, nullptr, ru_param + 3 * 128, 640, ru_bias, RU, 128, 1, 0, 1, nullptr, nullptr);
  build_x0_ru<<<gBuild, 256, 0, stream>>>(x, h, A);    // rebuild X0
  propagate_ck<<<gp1, 256, 0, stream>>>(A, Bx, xs_b1, rp_b, col_b, wb, 1.f, WROWU);
  gemm_k96<<<g1, 256, 0, stream>>>((const uint2*)Bx, nullptr, nullptr, ru_param + 2 * 128, 640, ru_bias, RU, 128, 1, 0, 1, nullptr, nullptr);
  propagate_ck<<<gp1, 256, 0, stream>>>(Bx, A, xs_b2, rp_b, col_b, wb, 2.f, WROWU);
  gemm_k96<<<g1, 256, 0, stream>>>((const uint2*)A, nullptr, nullptr, ru_param + 4 * 128, 640, ru_bias, RU, 128, 2, 0, 1, nullptr, nullptr); // + sigmoid

  // ===== conv2 (c) =====
  if (reuse) {
    const int gp2 = 2 * Nn;              // rh-only propagate grid (2 chunks)
    build_xbf<<<Nn * 256 / 256, 256, 0, stream>>>(x, xbf);
    build_rh<<<Nn * 512 / 256, 256, 0, stream>>>(h, RU, rh0);
    gemm_k96<<<g2, 256, 0, stream>>>(nullptr, (const uint2*)xbf, (const uint2*)rh0, wc0, 64, c_bias, outp, 64, 0, 1, 0, nullptr, nullptr);
    propagate_ck<<<gp2, 256, 0, stream>>>(rh0, rhA, nullptr, rp_f, col_f, wf, 1.f, RHU);
    gemm_k96<<<g2, 256, 0, stream>>>(nullptr, (const uint2*)xs_f1, (const uint2*)rhA, c_param + 1 * 64, 320, c_bias, outp, 64, 1, 1, 0, nullptr, nullptr);
    propagate_ck<<<gp2, 256, 0, stream>>>(rhA, rhB, nullptr, rp_f, col_f, wf, 2.f, RHU);
    gemm_k96<<<g2, 256, 0, stream>>>(nullptr, (const uint2*)xs_f2, (const uint2*)rhB, c_param + 3 * 64, 320, c_bias, outp, 64, 1, 1, 0, nullptr, nullptr);
    propagate_ck<<<gp2, 256, 0, stream>>>(rh0, rhA, nullptr, rp_b, col_b, wb, 1.f, RHU);
    gemm_k96<<<g2, 256, 0, stream>>>(nullptr, (const uint2*)xs_b1, (const uint2*)rhA, c_param + 2 * 64, 320, c_bias, outp, 64, 1, 1, 0, nullptr, nullptr);
    propagate_ck<<<gp2, 256, 0, stream>>>(rhA, rhB, nullptr, rp_b, col_b, wb, 2.f, RHU);
    gemm_k96<<<g2, 256, 0, stream>>>(nullptr, (const uint2*)xs_b2, (const uint2*)rhB, c_param + 4 * 64, 320, c_bias, outp, 64, 3, 1, 0, RUs, h); // fused GRU
  } else {
    build_x0_c<<<gBuild, 256, 0, stream>>>(x, h, RU, A);
    gemm_k96<<<g2, 256, 0, stream>>>((const uint2*)A, nullptr, nullptr, wc0, 64, c_bias, outp, 64, 0, 1, 0, nullptr, nullptr);
    propagate_ck<<<gp1, 256, 0, stream>>>(A, Bx, nullptr, rp_f, col_f, wf, 1.f, WROWU);
    gemm_k96<<<g2, 256, 0, stream>>>((const uint2*)Bx, nullptr, nullptr, c_param + 1 * 64, 320, c_bias, outp, 64, 1, 1, 0, nullptr, nullptr);
    propagate_ck<<<gp1, 256, 0, stream>>>(Bx, A, nullptr, rp_f, col_f, wf, 2.f, WROWU);
    gemm_k96<<<g2, 256, 0, stream>>>((const uint2*)A, nullptr, nullptr, c_param + 3 * 64, 320, c_bias, outp, 64, 1, 1, 0, nullptr, nullptr);
    build_x0_c<<<gBuild, 256, 0, stream>>>(x, h, RU, A);
    propagate_ck<<<gp1, 256, 0, stream>>>(A, Bx, nullptr, rp_b, col_b, wb, 1.f, WROWU);
    gemm_k96<<<g2, 256, 0, stream>>>((const uint2*)Bx, nullptr, nullptr, c_param + 2 * 64, 320, c_bias, outp, 64, 1, 1, 0, nullptr, nullptr);
    propagate_ck<<<gp1, 256, 0, stream>>>(Bx, A, nullptr, rp_b, col_b, wb, 2.f, WROWU);
    gemm_k96<<<g2, 256, 0, stream>>>((const uint2*)A, nullptr, nullptr, c_param + 4 * 64, 320, c_bias, outp, 64, 3, 1, 0, RUs, h); // fused GRU
  }
}

// Round 4
// 1630.963 us; speedup vs baseline: 1.2177x; 1.0291x over previous
//
#include <hip/hip_runtime.h>
#include <stdint.h>
#include <stddef.h>

#define Bn    16
#define Nn    10000
#define En    320000
#define CIN   32
#define COUTn 64
#define CCn   96            // CIN + COUT
#define WROWU 768           // uints per full node row (16 batches * 96ch / 2)
#define RHU   512           // uints per rh-only node row (16 * 64 / 2)
#define MROWS 160000        // Nn * Bn

// ---------------- bf16 helpers ----------------
__device__ __forceinline__ float bflo(unsigned int p) { return __uint_as_float(p << 16); }
__device__ __forceinline__ float bfhi(unsigned int p) { return __uint_as_float(p & 0xffff0000u); }
__device__ __forceinline__ float bf2f(unsigned short u) { return __uint_as_float(((unsigned int)u) << 16); }
__device__ __forceinline__ unsigned int f2bfbits(float f) {
  unsigned int x = __float_as_uint(f);
  return (x + 0x7fffu + ((x >> 16) & 1u)) >> 16;
}
__device__ __forceinline__ unsigned int pack2(float lo, float hi) {
  return f2bfbits(lo) | (f2bfbits(hi) << 16);
}

// ---------------- edge_index dtype detection ----------------
__global__ void detect_idx(const int* __restrict__ idx, int* __restrict__ flag) {
  if (threadIdx.x == 0 && blockIdx.x == 0) {
    int is64 = 1;
    for (int i = 1; i < 128; i += 2) {
      if (idx[i] != 0) { is64 = 0; break; }
    }
    flag[0] = is64;
  }
}

__device__ __forceinline__ int gidx(const int* __restrict__ p, int i, int is64) {
  return is64 ? p[2 * (long long)i] : p[i];
}

// ---------------- degree + CSR row counts ----------------
__global__ void deg_cnt_kernel(const int* __restrict__ idx, const float* __restrict__ w,
                               float* __restrict__ deg_f, float* __restrict__ deg_b,
                               int* __restrict__ cnt_f, int* __restrict__ cnt_b,
                               const int* __restrict__ flag) {
  int e = blockIdx.x * 256 + threadIdx.x;
  int is64 = flag[0];
  if (e < En) {
    int s = gidx(idx, e, is64);
    int d = gidx(idx, En + e, is64);
    float we = w[e];
    atomicAdd(&deg_f[s], we);
    atomicAdd(&deg_b[d], we);
    atomicAdd(&cnt_f[d], 1);
    atomicAdd(&cnt_b[s], 1);
  }
}

// ---------------- exclusive scan ----------------
__global__ void exscan_two(const int* __restrict__ cnt_f, const int* __restrict__ cnt_b,
                           int* __restrict__ rp_f, int* __restrict__ rp_b,
                           int* __restrict__ cur_f, int* __restrict__ cur_b, int n) {
  const int* cnt = (blockIdx.x == 0) ? cnt_f : cnt_b;
  int* rp  = (blockIdx.x == 0) ? rp_f  : rp_b;
  int* cur = (blockIdx.x == 0) ? cur_f : cur_b;
  __shared__ int sh[256];
  int t = threadIdx.x;
  int running = 0;
  for (int base = 0; base < n; base += 256) {
    int v = (base + t < n) ? cnt[base + t] : 0;
    sh[t] = v;
    __syncthreads();
    for (int off = 1; off < 256; off <<= 1) {
      int x = (t >= off) ? sh[t - off] : 0;
      __syncthreads();
      sh[t] += x;
      __syncthreads();
    }
    int excl = sh[t] - v;
    if (base + t < n) { rp[base + t] = running + excl; cur[base + t] = running + excl; }
    int total = sh[255];
    __syncthreads();
    running += total;
  }
  if (t == 0) rp[n] = running;
}

// ---------------- CSR fill ----------------
__global__ void fill_csr(const int* __restrict__ idx, const float* __restrict__ w,
                         const float* __restrict__ deg_f, const float* __restrict__ deg_b,
                         int* __restrict__ cur_f, int* __restrict__ cur_b,
                         int* __restrict__ col_f, float* __restrict__ wf,
                         int* __restrict__ col_b, float* __restrict__ wb,
                         const int* __restrict__ flag) {
  int e = blockIdx.x * 256 + threadIdx.x;
  int is64 = flag[0];
  if (e < En) {
    int s = gidx(idx, e, is64);
    int d = gidx(idx, En + e, is64);
    float we = w[e];
    int pf = atomicAdd(&cur_f[d], 1);
    col_f[pf] = s;
    wf[pf] = we / deg_f[s];
    int pb = atomicAdd(&cur_b[s], 1);
    col_b[pb] = d;
    wb[pb] = we / deg_b[d];
  }
}

// ---------------- fold W0' = W0 - W3 - W4 ----------------
__global__ void fold_w0(const float* __restrict__ ru_p, const float* __restrict__ c_p,
                        float* __restrict__ wru, float* __restrict__ wc) {
  int i = blockIdx.x * 256 + threadIdx.x;
  if (i < 96 * 128) {
    int k = i / 128, c = i % 128;
    wru[i] = ru_p[(k * 5 + 0) * 128 + c] - ru_p[(k * 5 + 3) * 128 + c] - ru_p[(k * 5 + 4) * 128 + c];
  }
  if (i < 96 * 64) {
    int k = i / 64, c = i % 64;
    wc[i] = c_p[(k * 5 + 0) * 64 + c] - c_p[(k * 5 + 3) * 64 + c] - c_p[(k * 5 + 4) * 64 + c];
  }
}

// ---------------- X0 builders ----------------
__global__ void build_x0_ru(const float* __restrict__ x, const float* __restrict__ h,
                            unsigned int* __restrict__ X0) {
  long long p = (long long)blockIdx.x * 256 + threadIdx.x;
  int node = (int)(p / WROWU);
  int rem = (int)(p % WROWU);
  int b = rem / 48;
  int ci = (rem % 48) * 2;
  float lo, hi;
  if (ci < CIN) {
    const float* s = x + ((size_t)b * Nn + node) * CIN + ci;
    lo = s[0]; hi = s[1];
  } else {
    const float* s = h + ((size_t)b * Nn + node) * COUTn + (ci - CIN);
    lo = s[0]; hi = s[1];
  }
  X0[p] = pack2(lo, hi);
}

// full-width [x, r*h] (fallback path only)
__global__ void build_x0_c(const float* __restrict__ x, const float* __restrict__ h,
                           const unsigned int* __restrict__ RU, unsigned int* __restrict__ X0) {
  long long p = (long long)blockIdx.x * 256 + threadIdx.x;
  int node = (int)(p / WROWU);
  int rem = (int)(p % WROWU);
  int b = rem / 48;
  int ci = (rem % 48) * 2;
  float lo, hi;
  if (ci < CIN) {
    const float* s = x + ((size_t)b * Nn + node) * CIN + ci;
    lo = s[0]; hi = s[1];
  } else {
    int o = ci - CIN;
    unsigned int rp = RU[((size_t)node * Bn + b) * 64 + (o >> 1)];
    const float* s = h + ((size_t)b * Nn + node) * COUTn + o;
    lo = bflo(rp) * s[0];
    hi = bfhi(rp) * s[1];
  }
  X0[p] = pack2(lo, hi);
}

// fallback-only builders
__global__ void build_rh(const float* __restrict__ h, const unsigned int* __restrict__ RU,
                         unsigned int* __restrict__ rh) {
  long long q = (long long)blockIdx.x * 256 + threadIdx.x;
  int node = (int)(q >> 9);
  int rem = (int)(q & 511);
  int b = rem >> 5;
  int ou = rem & 31;
  int o = ou * 2;
  unsigned int rp = RU[((size_t)node * Bn + b) * 64 + ou];
  const float* hs = h + ((size_t)b * Nn + node) * COUTn + o;
  rh[q] = pack2(bflo(rp) * hs[0], bfhi(rp) * hs[1]);
}

__global__ void build_xbf(const float* __restrict__ x, unsigned int* __restrict__ xbf) {
  long long q = (long long)blockIdx.x * 256 + threadIdx.x;
  int node = (int)(q >> 8);
  int rem = (int)(q & 255);
  int b = rem >> 4;
  int ci = (rem & 15) * 2;
  const float* xs = x + ((size_t)b * Nn + node) * CIN + ci;
  xbf[q] = pack2(xs[0], xs[1]);
}

// ---------------- chunked propagate (single direction) ----------------
__launch_bounds__(256)
__global__ void propagate_ck(const unsigned int* __restrict__ in, unsigned int* __restrict__ out,
                             unsigned int* __restrict__ xsave,
                             const int* __restrict__ rowptr, const int* __restrict__ col,
                             const float* __restrict__ w, float alpha, int rowU) {
  __shared__ int scol[256];
  __shared__ float sw[256];
  int row = blockIdx.x % Nn;
  int chunk = blockIdx.x / Nn;
  int t = threadIdx.x;
  int uoff = chunk * 256 + t;
  float alo = 0.f, ahi = 0.f;
  int jb = rowptr[row], je = rowptr[row + 1];
  for (int base = jb; base < je; base += 256) {
    int m = je - base; if (m > 256) m = 256;
    __syncthreads();
    if (t < m) { scol[t] = col[base + t]; sw[t] = w[base + t]; }
    __syncthreads();
    int j = 0;
    for (; j + 4 <= m; j += 4) {
      unsigned int p0 = in[(size_t)scol[j + 0] * rowU + uoff];
      unsigned int p1 = in[(size_t)scol[j + 1] * rowU + uoff];
      unsigned int p2 = in[(size_t)scol[j + 2] * rowU + uoff];
      unsigned int p3 = in[(size_t)scol[j + 3] * rowU + uoff];
      float w0 = sw[j + 0], w1 = sw[j + 1], w2 = sw[j + 2], w3 = sw[j + 3];
      alo += w0 * bflo(p0); ahi += w0 * bfhi(p0);
      alo += w1 * bflo(p1); ahi += w1 * bfhi(p1);
      alo += w2 * bflo(p2); ahi += w2 * bfhi(p2);
      alo += w3 * bflo(p3); ahi += w3 * bfhi(p3);
    }
    for (; j < m; ++j) {
      unsigned int p0 = in[(size_t)scol[j] * rowU + uoff];
      float w0 = sw[j];
      alo += w0 * bflo(p0); ahi += w0 * bfhi(p0);
    }
  }
  unsigned int o = pack2(alpha * alo, alpha * ahi);
  out[(size_t)row * rowU + uoff] = o;
  if (xsave) {
    int b = uoff / 48;
    int r = uoff % 48;
    if (r < 16) xsave[(size_t)row * 256 + b * 16 + r] = o;
  }
}

// ---------------- dual-direction propagate (x1f & x1b from the same input) ----------------
__launch_bounds__(256)
__global__ void propagate_dual(const unsigned int* __restrict__ in,
                               unsigned int* __restrict__ outF, unsigned int* __restrict__ outB,
                               const int* __restrict__ rp_f, const int* __restrict__ col_f,
                               const float* __restrict__ wf,
                               const int* __restrict__ rp_b, const int* __restrict__ col_b,
                               const float* __restrict__ wb, int rowU) {
  __shared__ int scol[256];
  __shared__ float sw[256];
  int row = blockIdx.x % Nn;
  int chunk = blockIdx.x / Nn;
  int t = threadIdx.x;
  int uoff = chunk * 256 + t;
  // forward
  {
    float alo = 0.f, ahi = 0.f;
    int jb = rp_f[row], je = rp_f[row + 1];
    for (int base = jb; base < je; base += 256) {
      int m = je - base; if (m > 256) m = 256;
      __syncthreads();
      if (t < m) { scol[t] = col_f[base + t]; sw[t] = wf[base + t]; }
      __syncthreads();
      int j = 0;
      for (; j + 4 <= m; j += 4) {
        unsigned int p0 = in[(size_t)scol[j + 0] * rowU + uoff];
        unsigned int p1 = in[(size_t)scol[j + 1] * rowU + uoff];
        unsigned int p2 = in[(size_t)scol[j + 2] * rowU + uoff];
        unsigned int p3 = in[(size_t)scol[j + 3] * rowU + uoff];
        float w0 = sw[j + 0], w1 = sw[j + 1], w2 = sw[j + 2], w3 = sw[j + 3];
        alo += w0 * bflo(p0); ahi += w0 * bfhi(p0);
        alo += w1 * bflo(p1); ahi += w1 * bfhi(p1);
        alo += w2 * bflo(p2); ahi += w2 * bfhi(p2);
        alo += w3 * bflo(p3); ahi += w3 * bfhi(p3);
      }
      for (; j < m; ++j) {
        unsigned int p0 = in[(size_t)scol[j] * rowU + uoff];
        float w0 = sw[j];
        alo += w0 * bflo(p0); ahi += w0 * bfhi(p0);
      }
    }
    outF[(size_t)row * rowU + uoff] = pack2(alo, ahi);
  }
  // backward
  {
    float alo = 0.f, ahi = 0.f;
    int jb = rp_b[row], je = rp_b[row + 1];
    for (int base = jb; base < je; base += 256) {
      int m = je - base; if (m > 256) m = 256;
      __syncthreads();
      if (t < m) { scol[t] = col_b[base + t]; sw[t] = wb[base + t]; }
      __syncthreads();
      int j = 0;
      for (; j + 4 <= m; j += 4) {
        unsigned int p0 = in[(size_t)scol[j + 0] * rowU + uoff];
        unsigned int p1 = in[(size_t)scol[j + 1] * rowU + uoff];
        unsigned int p2 = in[(size_t)scol[j + 2] * rowU + uoff];
        unsigned int p3 = in[(size_t)scol[j + 3] * rowU + uoff];
        float w0 = sw[j + 0], w1 = sw[j + 1], w2 = sw[j + 2], w3 = sw[j + 3];
        alo += w0 * bflo(p0); ahi += w0 * bfhi(p0);
        alo += w1 * bflo(p1); ahi += w1 * bfhi(p1);
        alo += w2 * bflo(p2); ahi += w2 * bfhi(p2);
        alo += w3 * bflo(p3); ahi += w3 * bfhi(p3);
      }
      for (; j < m; ++j) {
        unsigned int p0 = in[(size_t)scol[j] * rowU + uoff];
        float w0 = sw[j];
        alo += w0 * bflo(p0); ahi += w0 * bfhi(p0);
      }
    }
    outB[(size_t)row * rowU + uoff] = pack2(alo, ahi);
  }
}

// ---------------- multi-term GEMM (rich path) ----------------
// Accumulates sum over terms t of X_t[row,:96] @ P_t into a 64x64 C tile.
// X_t source: full-width buffer (rh==null): M x 96 bf16 rows (24 uint2 each);
//             or split: x-part = first 16 uints of each (node,b) 48-uint segment of xs,
//                       rh-part = compact rh buffer (node*256 + b*16 uint2).
// P_t: lp==0 -> Pf (folded W0'), stride nld; else Pm + lp*nld, stride 5*nld.
// mode 0: conv1 epilogue: v=sigmoid(bias+acc); n0==0 -> rh0=v*h (bf16); n0==64 -> U=v (bf16)
// mode 1: outp = bias + acc (f32, batch-major)
// mode 2: cp = outp + acc; c=tanh(tanh(cp)); u from U; outp = u*h + (1-u)*c
struct Gsrc {
  const uint2* xs[5];
  const uint2* rh[5];
  int lp[5];
};

__launch_bounds__(256)
__global__ void gemm_mega(Gsrc g, int nt, const float* __restrict__ Pf,
                          const float* __restrict__ Pm, int nld,
                          const float* __restrict__ bias,
                          float* __restrict__ outp,
                          unsigned int* __restrict__ rh0_u, unsigned int* __restrict__ U_u,
                          const unsigned short* __restrict__ U_s,
                          const float* __restrict__ hglob, int mode) {
  __shared__ float XsT[96][68];
  __shared__ float Ps[96][64];

  int m0 = blockIdx.x * 64;
  int n0 = blockIdx.y * 64;
  int tid = threadIdx.x;
  int tx = tid % 16;
  int ty = tid / 16;
  int nodeBase = m0 >> 4;

  float acc[4][4];
  #pragma unroll
  for (int i = 0; i < 4; ++i)
    #pragma unroll
    for (int j = 0; j < 4; ++j) acc[i][j] = 0.f;

  for (int t = 0; t < nt; ++t) {
    __syncthreads();
    const uint2* xsp = g.xs[t];
    const uint2* rhp = g.rh[t];
    if (rhp == nullptr) {
      const uint2* Xt = xsp + (size_t)m0 * 24;
      #pragma unroll
      for (int it = 0; it < 6; ++it) {
        int q = tid + it * 256;
        uint2 v = Xt[q];
        int g4 = q * 4;
        int r = g4 / 96;
        int k = g4 % 96;
        XsT[k + 0][r] = bflo(v.x);
        XsT[k + 1][r] = bfhi(v.x);
        XsT[k + 2][r] = bflo(v.y);
        XsT[k + 3][r] = bfhi(v.y);
      }
    } else {
      #pragma unroll
      for (int it = 0; it < 6; ++it) {
        int q = tid + it * 256;
        int node_l = q / 384;
        int rq = q % 384;
        uint2 v; int b, ci0;
        if (rq < 128) {          // x-part: 8 uint2 per (node,b), from full-width term buf
          b = rq >> 3;
          int u2i = rq & 7;
          v = xsp[(size_t)(nodeBase + node_l) * 384 + b * 24 + u2i];
          ci0 = u2i * 4;
        } else {                 // rh-part: 16 uint2 per (node,b), compact
          int rr = rq - 128;
          b = rr >> 4;
          int u2i = rr & 15;
          v = rhp[(size_t)(nodeBase + node_l) * 256 + b * 16 + u2i];
          ci0 = 32 + u2i * 4;
        }
        int r = node_l * 16 + b;
        XsT[ci0 + 0][r] = bflo(v.x);
        XsT[ci0 + 1][r] = bfhi(v.x);
        XsT[ci0 + 2][r] = bflo(v.y);
        XsT[ci0 + 3][r] = bfhi(v.y);
      }
    }
    {
      int lp = g.lp[t];
      const float* Pl = (lp == 0) ? Pf : (Pm + (size_t)lp * nld);
      int prs = (lp == 0) ? nld : 5 * nld;
      #pragma unroll
      for (int it = 0; it < 6; ++it) {
        int q = tid + it * 256;
        int kk = q / 16;
        int nn = (q % 16) * 4;
        float4 v = *(const float4*)(Pl + (size_t)kk * prs + n0 + nn);
        *(float4*)&Ps[kk][nn] = v;
      }
    }
    __syncthreads();

    #pragma unroll 4
    for (int k = 0; k < 96; ++k) {
      float4 a = *(const float4*)&XsT[k][ty * 4];
      float4 b = *(const float4*)&Ps[k][tx * 4];
      acc[0][0] += a.x * b.x; acc[0][1] += a.x * b.y; acc[0][2] += a.x * b.z; acc[0][3] += a.x * b.w;
      acc[1][0] += a.y * b.x; acc[1][1] += a.y * b.y; acc[1][2] += a.y * b.z; acc[1][3] += a.y * b.w;
      acc[2][0] += a.z * b.x; acc[2][1] += a.z * b.y; acc[2][2] += a.z * b.z; acc[2][3] += a.z * b.w;
      acc[3][0] += a.w * b.x; acc[3][1] += a.w * b.y; acc[3][2] += a.w * b.z; acc[3][3] += a.w * b.w;
    }
  }

  #pragma unroll
  for (int i = 0; i < 4; ++i) {
    int row = m0 + ty * 4 + i;
    int node = row >> 4, b = row & 15;
    int cg0 = n0 + tx * 4;
    if (mode == 0) {
      float v0 = 1.f / (1.f + expf(-(bias[cg0 + 0] + acc[i][0])));
      float v1 = 1.f / (1.f + expf(-(bias[cg0 + 1] + acc[i][1])));
      float v2 = 1.f / (1.f + expf(-(bias[cg0 + 2] + acc[i][2])));
      float v3 = 1.f / (1.f + expf(-(bias[cg0 + 3] + acc[i][3])));
      if (n0 == 0) {   // r columns -> rh = r*h
        const float* hs = hglob + ((size_t)b * Nn + node) * COUTn + cg0;
        v0 *= hs[0]; v1 *= hs[1]; v2 *= hs[2]; v3 *= hs[3];
        unsigned int* o = rh0_u + (size_t)node * 512 + b * 32 + (cg0 >> 1);
        o[0] = pack2(v0, v1);
        o[1] = pack2(v2, v3);
      } else {         // u columns
        int cu = cg0 - 64;
        unsigned int* o = U_u + (size_t)node * 512 + b * 32 + (cu >> 1);
        o[0] = pack2(v0, v1);
        o[1] = pack2(v2, v3);
      }
    } else if (mode == 1) {
      float* o = outp + ((size_t)b * Nn + node) * COUTn + cg0;
      o[0] = bias[cg0 + 0] + acc[i][0];
      o[1] = bias[cg0 + 1] + acc[i][1];
      o[2] = bias[cg0 + 2] + acc[i][2];
      o[3] = bias[cg0 + 3] + acc[i][3];
    } else {           // mode 2: fused GRU final
      float* o = outp + ((size_t)b * Nn + node) * COUTn + cg0;
      const float* hs = hglob + ((size_t)b * Nn + node) * COUTn + cg0;
      const unsigned short* us = U_s + (size_t)node * 1024 + b * 64 + cg0;
      #pragma unroll
      for (int j = 0; j < 4; ++j) {
        float cp = o[j] + acc[i][j];
        float c = tanhf(tanhf(cp));
        float u = bf2f(us[j]);
        o[j] = u * hs[j] + (1.f - u) * c;
      }
    }
  }
}

// ---------------- fallback GEMM (round-3, proven) ----------------
__launch_bounds__(256)
__global__ void gemm_k96(const uint2* __restrict__ Xc, const uint2* __restrict__ Xp,
                         const uint2* __restrict__ Rh,
                         const float* __restrict__ P, int prs,
                         const float* __restrict__ bias,
                         void* __restrict__ C, int ldc, int mode, int out_bn, int cbf16,
                         const unsigned short* __restrict__ RUb, const float* __restrict__ hg) {
  __shared__ float XsT[96][68];
  __shared__ float Ps[96][64];

  int m0 = blockIdx.x * 64;
  int n0 = blockIdx.y * 64;
  int tid = threadIdx.x;
  int tx = tid % 16;
  int ty = tid / 16;

  if (Xc) {
    const uint2* Xt = Xc + (size_t)m0 * 24;
    #pragma unroll
    for (int it = 0; it < 6; ++it) {
      int q = tid + it * 256;
      uint2 v = Xt[q];
      int g = q * 4;
      int r = g / 96;
      int k = g % 96;
      XsT[k + 0][r] = bflo(v.x);
      XsT[k + 1][r] = bfhi(v.x);
      XsT[k + 2][r] = bflo(v.y);
      XsT[k + 3][r] = bfhi(v.y);
    }
  } else {
    int nodeBase = m0 >> 4;
    #pragma unroll
    for (int it = 0; it < 6; ++it) {
      int q = tid + it * 256;
      int node_l = q / 384;
      int rq = q % 384;
      uint2 v; int b, ci0;
      if (rq < 128) {
        b = rq >> 3; ci0 = (rq & 7) * 4;
        v = Xp[(size_t)(nodeBase + node_l) * 128 + rq];
      } else {
        int rr = rq - 128;
        b = rr >> 4; ci0 = 32 + (rr & 15) * 4;
        v = Rh[(size_t)(nodeBase + node_l) * 256 + rr];
      }
      int r = node_l * 16 + b;
      XsT[ci0 + 0][r] = bflo(v.x);
      XsT[ci0 + 1][r] = bfhi(v.x);
      XsT[ci0 + 2][r] = bflo(v.y);
      XsT[ci0 + 3][r] = bfhi(v.y);
    }
  }
  {
    #pragma unroll
    for (int it = 0; it < 6; ++it) {
      int q = tid + it * 256;
      int kk = q / 16;
      int nn = (q % 16) * 4;
      float4 v = *(const float4*)(P + (size_t)kk * prs + n0 + nn);
      *(float4*)&Ps[kk][nn] = v;
    }
  }
  __syncthreads();

  float acc[4][4];
  #pragma unroll
  for (int i = 0; i < 4; ++i)
    #pragma unroll
    for (int j = 0; j < 4; ++j) acc[i][j] = 0.f;

  #pragma unroll 4
  for (int k = 0; k < 96; ++k) {
    float4 a = *(const float4*)&XsT[k][ty * 4];
    float4 b = *(const float4*)&Ps[k][tx * 4];
    acc[0][0] += a.x * b.x; acc[0][1] += a.x * b.y; acc[0][2] += a.x * b.z; acc[0][3] += a.x * b.w;
    acc[1][0] += a.y * b.x; acc[1][1] += a.y * b.y; acc[1][2] += a.y * b.z; acc[1][3] += a.y * b.w;
    acc[2][0] += a.z * b.x; acc[2][1] += a.z * b.y; acc[2][2] += a.z * b.z; acc[2][3] += a.z * b.w;
    acc[3][0] += a.w * b.x; acc[3][1] += a.w * b.y; acc[3][2] += a.w * b.z; acc[3][3] += a.w * b.w;
  }

  #pragma unroll
  for (int i = 0; i < 4; ++i) {
    int row = m0 + ty * 4 + i;
    #pragma unroll
    for (int j = 0; j < 4; ++j) {
      int cg = n0 + tx * 4 + j;
      if (mode == 3) {
        int node = row >> 4, b = row & 15;
        size_t oaddr = ((size_t)b * Nn + node) * 64 + cg;
        float* Cf = (float*)C;
        float cp = Cf[oaddr] + acc[i][j];
        float cc = tanhf(tanhf(cp));
        float u = bf2f(RUb[(size_t)row * 128 + 64 + cg]);
        Cf[oaddr] = u * hg[oaddr] + (1.f - u) * cc;
      } else if (mode == 2) {
        unsigned short* Cp = (unsigned short*)C;
        size_t addr = (size_t)row * ldc + cg;
        float v = bf2f(Cp[addr]) + acc[i][j];
        v = 1.f / (1.f + expf(-v));
        Cp[addr] = (unsigned short)f2bfbits(v);
      } else {
        size_t addr;
        if (out_bn) addr = ((size_t)((row & 15) * Nn + (row >> 4))) * ldc + cg;
        else        addr = (size_t)row * ldc + cg;
        if (cbf16) {
          unsigned short* Cp = (unsigned short*)C;
          float v = (mode == 0) ? (bias[cg] + acc[i][j]) : (bf2f(Cp[addr]) + acc[i][j]);
          Cp[addr] = (unsigned short)f2bfbits(v);
        } else {
          float* Cf = (float*)C;
          float v = (mode == 0) ? (bias[cg] + acc[i][j]) : (Cf[addr] + acc[i][j]);
          Cf[addr] = v;
        }
      }
    }
  }
}

// ---------------- host ----------------
extern "C" void kernel_launch(void* const* d_in, const int* in_sizes, int n_in,
                              void* d_out, int out_size, void* d_ws, size_t ws_size,
                              hipStream_t stream) {
  const float* x   = (const float*)d_in[0];
  const float* h   = (const float*)d_in[1];
  const int*   idx = (const int*)d_in[2];
  const float* ew  = (const float*)d_in[3];
  const float* ru_param = (const float*)d_in[4];
  const float* ru_bias  = (const float*)d_in[5];
  const float* c_param  = (const float*)d_in[6];
  const float* c_bias   = (const float*)d_in[7];
  float* outp = (float*)d_out;
  (void)in_sizes; (void)n_in; (void)out_size;

  char* ws = (char*)d_ws;
  size_t off = 0;
  auto alloc = [&](size_t bytes) -> char* {
    char* p = ws + off;
    off += (bytes + 255) & ~(size_t)255;
    return p;
  };

  float* deg_f = (float*)alloc(40960);
  float* deg_b = (float*)alloc(40960);
  int*   cnt_f = (int*)alloc(40960);
  int*   cnt_b = (int*)alloc(40960);
  int*   rp_f  = (int*)alloc((Nn + 1) * sizeof(int));
  int*   rp_b  = (int*)alloc((Nn + 1) * sizeof(int));
  int*   cur_f = (int*)alloc(Nn * sizeof(int));
  int*   cur_b = (int*)alloc(Nn * sizeof(int));
  int*   flag  = (int*)alloc(256);
  int*   col_f = (int*)alloc(En * sizeof(int));
  float* wf    = (float*)alloc(En * sizeof(float));
  int*   col_b = (int*)alloc(En * sizeof(int));
  float* wb    = (float*)alloc(En * sizeof(float));
  float* wru0  = (float*)alloc(96 * 128 * sizeof(float));
  float* wc0   = (float*)alloc(96 * 64 * sizeof(float));

  hipMemsetAsync(ws, 0, 4 * 40960, stream);
  detect_idx<<<1, 64, 0, stream>>>(idx, flag);
  deg_cnt_kernel<<<En / 256, 256, 0, stream>>>(idx, ew, deg_f, deg_b, cnt_f, cnt_b, flag);
  exscan_two<<<2, 256, 0, stream>>>(cnt_f, cnt_b, rp_f, rp_b, cur_f, cur_b, Nn);
  fill_csr<<<En / 256, 256, 0, stream>>>(idx, ew, deg_f, deg_b, cur_f, cur_b,
                                         col_f, wf, col_b, wb, flag);
  fold_w0<<<48, 256, 0, stream>>>(ru_param, c_param, wru0, wc0);

  const int gBuild = Nn * WROWU / 256;
  bool rich = ws_size >= (size_t)242 * 1024 * 1024;

  if (rich) {
    // 5 full-width term buffers + 3 rh buffers + U ; peak ~241 MB
    unsigned int* A0  = (unsigned int*)alloc((size_t)Nn * WROWU * 4);
    unsigned int* T1f = (unsigned int*)alloc((size_t)Nn * WROWU * 4);
    unsigned int* T1b = (unsigned int*)alloc((size_t)Nn * WROWU * 4);
    unsigned int* T2f = (unsigned int*)alloc((size_t)Nn * WROWU * 4);
    unsigned int* T2b = (unsigned int*)alloc((size_t)Nn * WROWU * 4);
    unsigned int* rh0 = (unsigned int*)alloc((size_t)Nn * RHU * 4);
    unsigned int* rh1f = (unsigned int*)alloc((size_t)Nn * RHU * 4);
    unsigned int* rh1b = (unsigned int*)alloc((size_t)Nn * RHU * 4);
    unsigned int* Ubuf = (unsigned int*)alloc((size_t)Nn * RHU * 4);

    // conv1 diffusion
    build_x0_ru<<<gBuild, 256, 0, stream>>>(x, h, A0);
    propagate_dual<<<3 * Nn, 256, 0, stream>>>(A0, T1f, T1b, rp_f, col_f, wf,
                                               rp_b, col_b, wb, WROWU);
    propagate_ck<<<3 * Nn, 256, 0, stream>>>(T1f, T2f, nullptr, rp_f, col_f, wf, 2.f, WROWU);
    propagate_ck<<<3 * Nn, 256, 0, stream>>>(T1b, T2b, nullptr, rp_b, col_b, wb, 2.f, WROWU);

    // conv1 projection: one K=480 GEMM, fused sigmoid + r*h + u-store
    Gsrc g1;
    g1.xs[0] = (const uint2*)A0;  g1.rh[0] = nullptr; g1.lp[0] = 0;
    g1.xs[1] = (const uint2*)T1f; g1.rh[1] = nullptr; g1.lp[1] = 1;
    g1.xs[2] = (const uint2*)T1b; g1.rh[2] = nullptr; g1.lp[2] = 2;
    g1.xs[3] = (const uint2*)T2f; g1.rh[3] = nullptr; g1.lp[3] = 3;
    g1.xs[4] = (const uint2*)T2b; g1.rh[4] = nullptr; g1.lp[4] = 4;
    gemm_mega<<<dim3(MROWS / 64, 2), 256, 0, stream>>>(
        g1, 5, wru0, ru_param, 128, ru_bias, nullptr, rh0, Ubuf, nullptr, h, 0);

    // conv2 diffusion on rh (x-parts reused from conv1 term buffers)
    propagate_dual<<<2 * Nn, 256, 0, stream>>>(rh0, rh1f, rh1b, rp_f, col_f, wf,
                                               rp_b, col_b, wb, RHU);

    // conv2 pass A: l = 0,1,2
    Gsrc g2a;
    g2a.xs[0] = (const uint2*)A0;  g2a.rh[0] = (const uint2*)rh0;  g2a.lp[0] = 0;
    g2a.xs[1] = (const uint2*)T1f; g2a.rh[1] = (const uint2*)rh1f; g2a.lp[1] = 1;
    g2a.xs[2] = (const uint2*)T1b; g2a.rh[2] = (const uint2*)rh1b; g2a.lp[2] = 2;
    gemm_mega<<<dim3(MROWS / 64, 1), 256, 0, stream>>>(
        g2a, 3, wc0, c_param, 64, c_bias, outp, nullptr, nullptr, nullptr, nullptr, 1);

    // rh second-order terms (overwrite rh0 / rh1f after pass A consumed them)
    propagate_ck<<<2 * Nn, 256, 0, stream>>>(rh1f, rh0, nullptr, rp_f, col_f, wf, 2.f, RHU);   // rh2f
    propagate_ck<<<2 * Nn, 256, 0, stream>>>(rh1b, rh1f, nullptr, rp_b, col_b, wb, 2.f, RHU);  // rh2b

    // conv2 pass B: l = 3,4 + fused GRU final
    Gsrc g2b;
    g2b.xs[0] = (const uint2*)T2f; g2b.rh[0] = (const uint2*)rh0;  g2b.lp[0] = 3;
    g2b.xs[1] = (const uint2*)T2b; g2b.rh[1] = (const uint2*)rh1f; g2b.lp[1] = 4;
    g2b.xs[2] = nullptr; g2b.rh[2] = nullptr; g2b.lp[2] = 0;
    gemm_mega<<<dim3(MROWS / 64, 1), 256, 0, stream>>>(
        g2b, 2, wc0, c_param, 64, c_bias, outp, nullptr, nullptr,
        (const unsigned short*)Ubuf, h, 2);
    return;
  }

  // ---------------- fallback: round-3 structure ----------------
  unsigned int* A  = (unsigned int*)alloc((size_t)Nn * WROWU * 4);
  unsigned int* Bx = (unsigned int*)alloc((size_t)Nn * WROWU * 4);
  unsigned int* RU = (unsigned int*)alloc((size_t)MROWS * 64 * 4);

  bool reuse = ws_size >= (size_t)176 * 1024 * 1024;
  unsigned int *xs_f1 = nullptr, *xs_f2 = nullptr, *xs_b1 = nullptr, *xs_b2 = nullptr, *xbf = nullptr;
  unsigned int *rh0 = nullptr, *rhA = nullptr, *rhB = nullptr;
  if (reuse) {
    xs_f1 = (unsigned int*)alloc((size_t)Nn * 256 * 4);
    xs_f2 = (unsigned int*)alloc((size_t)Nn * 256 * 4);
    xs_b1 = (unsigned int*)alloc((size_t)Nn * 256 * 4);
    xs_b2 = (unsigned int*)alloc((size_t)Nn * 256 * 4);
    xbf   = (unsigned int*)alloc((size_t)Nn * 256 * 4);
    rh0 = A;
    rhA = A + (size_t)Nn * RHU;
    rhB = A + (size_t)Nn * RHU * 2;
  }

  dim3 gg1(MROWS / 64, 2);
  dim3 gg2(MROWS / 64, 1);
  const int gp1 = 3 * Nn;
  const unsigned short* RUs = (const unsigned short*)RU;

  build_x0_ru<<<gBuild, 256, 0, stream>>>(x, h, A);
  gemm_k96<<<gg1, 256, 0, stream>>>((const uint2*)A, nullptr, nullptr, wru0, 128, ru_bias, RU, 128, 0, 0, 1, nullptr, nullptr);
  propagate_ck<<<gp1, 256, 0, stream>>>(A, Bx, xs_f1, rp_f, col_f, wf, 1.f, WROWU);
  gemm_k96<<<gg1, 256, 0, stream>>>((const uint2*)Bx, nullptr, nullptr, ru_param + 1 * 128, 640, ru_bias, RU, 128, 1, 0, 1, nullptr, nullptr);
  propagate_ck<<<gp1, 256, 0, stream>>>(Bx, A, xs_f2, rp_f, col_f, wf, 2.f, WROWU);
  gemm_k96<<<gg1, 256, 0, stream>>>((const uint2*)A, nullptr, nullptr, ru_param + 3 * 128, 640, ru_bias, RU, 128, 1, 0, 1, nullptr, nullptr);
  build_x0_ru<<<gBuild, 256, 0, stream>>>(x, h, A);
  propagate_ck<<<gp1, 256, 0, stream>>>(A, Bx, xs_b1, rp_b, col_b, wb, 1.f, WROWU);
  gemm_k96<<<gg1, 256, 0, stream>>>((const uint2*)Bx, nullptr, nullptr, ru_param + 2 * 128, 640, ru_bias, RU, 128, 1, 0, 1, nullptr, nullptr);
  propagate_ck<<<gp1, 256, 0, stream>>>(Bx, A, xs_b2, rp_b, col_b, wb, 2.f, WROWU);
  gemm_k96<<<gg1, 256, 0, stream>>>((const uint2*)A, nullptr, nullptr, ru_param + 4 * 128, 640, ru_bias, RU, 128, 2, 0, 1, nullptr, nullptr);

  if (reuse) {
    const int gp2 = 2 * Nn;
    build_xbf<<<Nn * 256 / 256, 256, 0, stream>>>(x, xbf);
    build_rh<<<Nn * 512 / 256, 256, 0, stream>>>(h, RU, rh0);
    gemm_k96<<<gg2, 256, 0, stream>>>(nullptr, (const uint2*)xbf, (const uint2*)rh0, wc0, 64, c_bias, outp, 64, 0, 1, 0, nullptr, nullptr);
    propagate_ck<<<gp2, 256, 0, stream>>>(rh0, rhA, nullptr, rp_f, col_f, wf, 1.f, RHU);
    gemm_k96<<<gg2, 256, 0, stream>>>(nullptr, (const uint2*)xs_f1, (const uint2*)rhA, c_param + 1 * 64, 320, c_bias, outp, 64, 1, 1, 0, nullptr, nullptr);
    propagate_ck<<<gp2, 256, 0, stream>>>(rhA, rhB, nullptr, rp_f, col_f, wf, 2.f, RHU);
    gemm_k96<<<gg2, 256, 0, stream>>>(nullptr, (const uint2*)xs_f2, (const uint2*)rhB, c_param + 3 * 64, 320, c_bias, outp, 64, 1, 1, 0, nullptr, nullptr);
    propagate_ck<<<gp2, 256, 0, stream>>>(rh0, rhA, nullptr, rp_b, col_b, wb, 1.f, RHU);
    gemm_k96<<<gg2, 256, 0, stream>>>(nullptr, (const uint2*)xs_b1, (const uint2*)rhA, c_param + 2 * 64, 320, c_bias, outp, 64, 1, 1, 0, nullptr, nullptr);
    propagate_ck<<<gp2, 256, 0, stream>>>(rhA, rhB, nullptr, rp_b, col_b, wb, 2.f, RHU);
    gemm_k96<<<gg2, 256, 0, stream>>>(nullptr, (const uint2*)xs_b2, (const uint2*)rhB, c_param + 4 * 64, 320, c_bias, outp, 64, 3, 1, 0, RUs, h);
  } else {
    build_x0_c<<<gBuild, 256, 0, stream>>>(x, h, RU, A);
    gemm_k96<<<gg2, 256, 0, stream>>>((const uint2*)A, nullptr, nullptr, wc0, 64, c_bias, outp, 64, 0, 1, 0, nullptr, nullptr);
    propagate_ck<<<gp1, 256, 0, stream>>>(A, Bx, nullptr, rp_f, col_f, wf, 1.f, WROWU);
    gemm_k96<<<gg2, 256, 0, stream>>>((const uint2*)Bx, nullptr, nullptr, c_param + 1 * 64, 320, c_bias, outp, 64, 1, 1, 0, nullptr, nullptr);
    propagate_ck<<<gp1, 256, 0, stream>>>(Bx, A, nullptr, rp_f, col_f, wf, 2.f, WROWU);
    gemm_k96<<<gg2, 256, 0, stream>>>((const uint2*)A, nullptr, nullptr, c_param + 3 * 64, 320, c_bias, outp, 64, 1, 1, 0, nullptr, nullptr);
    build_x0_c<<<gBuild, 256, 0, stream>>>(x, h, RU, A);
    propagate_ck<<<gp1, 256, 0, stream>>>(A, Bx, nullptr, rp_b, col_b, wb, 1.f, WROWU);
    gemm_k96<<<gg2, 256, 0, stream>>>((const uint2*)Bx, nullptr, nullptr, c_param + 2 * 64, 320, c_bias, outp, 64, 1, 1, 0, nullptr, nullptr);
    propagate_ck<<<gp1, 256, 0, stream>>>(Bx, A, nullptr, rp_b, col_b, wb, 2.f, WROWU);
    gemm_k96<<<gg2, 256, 0, stream>>>((const uint2*)A, nullptr, nullptr, c_param + 4 * 64, 320, c_bias, outp, 64, 3, 1, 0, RUs, h);
  }
}

// Round 6
// 1183.997 us; speedup vs baseline: 1.6774x; 1.3775x over previous
//
#include <hip/hip_runtime.h>
#include <stdint.h>
#include <stddef.h>

#define Bn    16
#define Nn    10000
#define En    320000
#define CIN   32
#define COUTn 64
#define CCn   96
#define WROWU 768           // uints per full node row (16 batches * 96ch / 2)
#define RHU   512           // uints per rh-only node row (16 * 64 / 2)
#define MROWS 160000        // Nn * Bn

typedef __attribute__((ext_vector_type(8))) short short8;   // 8 bf16 = 4 VGPRs
typedef __attribute__((ext_vector_type(4))) float f32x4;

// ---------------- bf16 helpers ----------------
__device__ __forceinline__ float bflo(unsigned int p) { return __uint_as_float(p << 16); }
__device__ __forceinline__ float bfhi(unsigned int p) { return __uint_as_float(p & 0xffff0000u); }
__device__ __forceinline__ float bf2f(unsigned short u) { return __uint_as_float(((unsigned int)u) << 16); }
__device__ __forceinline__ unsigned int f2bfbits(float f) {
  unsigned int x = __float_as_uint(f);
  return (x + 0x7fffu + ((x >> 16) & 1u)) >> 16;
}
__device__ __forceinline__ unsigned int pack2(float lo, float hi) {
  return f2bfbits(lo) | (f2bfbits(hi) << 16);
}

// ---------------- edge_index dtype detection ----------------
__global__ void detect_idx(const int* __restrict__ idx, int* __restrict__ flag) {
  if (threadIdx.x == 0 && blockIdx.x == 0) {
    int is64 = 1;
    for (int i = 1; i < 128; i += 2) {
      if (idx[i] != 0) { is64 = 0; break; }
    }
    flag[0] = is64;
  }
}

__device__ __forceinline__ int gidx(const int* __restrict__ p, int i, int is64) {
  return is64 ? p[2 * (long long)i] : p[i];
}

// ---------------- degree + CSR row counts ----------------
__global__ void deg_cnt_kernel(const int* __restrict__ idx, const float* __restrict__ w,
                               float* __restrict__ deg_f, float* __restrict__ deg_b,
                               int* __restrict__ cnt_f, int* __restrict__ cnt_b,
                               const int* __restrict__ flag) {
  int e = blockIdx.x * 256 + threadIdx.x;
  int is64 = flag[0];
  if (e < En) {
    int s = gidx(idx, e, is64);
    int d = gidx(idx, En + e, is64);
    float we = w[e];
    atomicAdd(&deg_f[s], we);
    atomicAdd(&deg_b[d], we);
    atomicAdd(&cnt_f[d], 1);
    atomicAdd(&cnt_b[s], 1);
  }
}

// ---------------- exclusive scan ----------------
__global__ void exscan_two(const int* __restrict__ cnt_f, const int* __restrict__ cnt_b,
                           int* __restrict__ rp_f, int* __restrict__ rp_b,
                           int* __restrict__ cur_f, int* __restrict__ cur_b, int n) {
  const int* cnt = (blockIdx.x == 0) ? cnt_f : cnt_b;
  int* rp  = (blockIdx.x == 0) ? rp_f  : rp_b;
  int* cur = (blockIdx.x == 0) ? cur_f : cur_b;
  __shared__ int sh[256];
  int t = threadIdx.x;
  int running = 0;
  for (int base = 0; base < n; base += 256) {
    int v = (base + t < n) ? cnt[base + t] : 0;
    sh[t] = v;
    __syncthreads();
    for (int off = 1; off < 256; off <<= 1) {
      int x = (t >= off) ? sh[t - off] : 0;
      __syncthreads();
      sh[t] += x;
      __syncthreads();
    }
    int excl = sh[t] - v;
    if (base + t < n) { rp[base + t] = running + excl; cur[base + t] = running + excl; }
    int total = sh[255];
    __syncthreads();
    running += total;
  }
  if (t == 0) rp[n] = running;
}

// ---------------- CSR fill ----------------
__global__ void fill_csr(const int* __restrict__ idx, const float* __restrict__ w,
                         const float* __restrict__ deg_f, const float* __restrict__ deg_b,
                         int* __restrict__ cur_f, int* __restrict__ cur_b,
                         int* __restrict__ col_f, float* __restrict__ wf,
                         int* __restrict__ col_b, float* __restrict__ wb,
                         const int* __restrict__ flag) {
  int e = blockIdx.x * 256 + threadIdx.x;
  int is64 = flag[0];
  if (e < En) {
    int s = gidx(idx, e, is64);
    int d = gidx(idx, En + e, is64);
    float we = w[e];
    int pf = atomicAdd(&cur_f[d], 1);
    col_f[pf] = s;
    wf[pf] = we / deg_f[s];
    int pb = atomicAdd(&cur_b[s], 1);
    col_b[pb] = d;
    wb[pb] = we / deg_b[d];
  }
}

// ---------------- weight prep: transposed bf16, W0 folded (W0-W3-W4) ----------------
// Wt1[n][k] n<128, k=t*96+kk ; Wt2[n][k] n<64
__global__ void build_wt(const float* __restrict__ ru_p, const float* __restrict__ c_p,
                         unsigned short* __restrict__ Wt1, unsigned short* __restrict__ Wt2) {
  int i = blockIdx.x * 256 + threadIdx.x;
  if (i < 128 * 480) {
    int n = i / 480, k = i % 480;
    int t = k / 96, kk = k % 96;
    float v;
    if (t == 0) v = ru_p[(kk * 5 + 0) * 128 + n] - ru_p[(kk * 5 + 3) * 128 + n] - ru_p[(kk * 5 + 4) * 128 + n];
    else        v = ru_p[(kk * 5 + t) * 128 + n];
    Wt1[i] = (unsigned short)f2bfbits(v);
  }
  if (i < 64 * 480) {
    int n = i / 480, k = i % 480;
    int t = k / 96, kk = k % 96;
    float v;
    if (t == 0) v = c_p[(kk * 5 + 0) * 64 + n] - c_p[(kk * 5 + 3) * 64 + n] - c_p[(kk * 5 + 4) * 64 + n];
    else        v = c_p[(kk * 5 + t) * 64 + n];
    Wt2[i] = (unsigned short)f2bfbits(v);
  }
}

// ---------------- X0 builder ----------------
__global__ void build_x0_ru(const float* __restrict__ x, const float* __restrict__ h,
                            unsigned int* __restrict__ X0) {
  long long p = (long long)blockIdx.x * 256 + threadIdx.x;
  int node = (int)(p / WROWU);
  int rem = (int)(p % WROWU);
  int b = rem / 48;
  int ci = (rem % 48) * 2;
  float lo, hi;
  if (ci < CIN) {
    const float* s = x + ((size_t)b * Nn + node) * CIN + ci;
    lo = s[0]; hi = s[1];
  } else {
    const float* s = h + ((size_t)b * Nn + node) * COUTn + (ci - CIN);
    lo = s[0]; hi = s[1];
  }
  X0[p] = pack2(lo, hi);
}

// ---------------- chunked propagate (single direction) ----------------
__launch_bounds__(256)
__global__ void propagate_ck(const unsigned int* __restrict__ in, unsigned int* __restrict__ out,
                             const int* __restrict__ rowptr, const int* __restrict__ col,
                             const float* __restrict__ w, float alpha, int rowU) {
  __shared__ int scol[256];
  __shared__ float sw[256];
  int row = blockIdx.x % Nn;
  int chunk = blockIdx.x / Nn;
  int t = threadIdx.x;
  int uoff = chunk * 256 + t;
  float alo = 0.f, ahi = 0.f;
  int jb = rowptr[row], je = rowptr[row + 1];
  for (int base = jb; base < je; base += 256) {
    int m = je - base; if (m > 256) m = 256;
    __syncthreads();
    if (t < m) { scol[t] = col[base + t]; sw[t] = w[base + t]; }
    __syncthreads();
    int j = 0;
    for (; j + 4 <= m; j += 4) {
      unsigned int p0 = in[(size_t)scol[j + 0] * rowU + uoff];
      unsigned int p1 = in[(size_t)scol[j + 1] * rowU + uoff];
      unsigned int p2 = in[(size_t)scol[j + 2] * rowU + uoff];
      unsigned int p3 = in[(size_t)scol[j + 3] * rowU + uoff];
      float w0 = sw[j + 0], w1 = sw[j + 1], w2 = sw[j + 2], w3 = sw[j + 3];
      alo += w0 * bflo(p0); ahi += w0 * bfhi(p0);
      alo += w1 * bflo(p1); ahi += w1 * bfhi(p1);
      alo += w2 * bflo(p2); ahi += w2 * bfhi(p2);
      alo += w3 * bflo(p3); ahi += w3 * bfhi(p3);
    }
    for (; j < m; ++j) {
      unsigned int p0 = in[(size_t)scol[j] * rowU + uoff];
      float w0 = sw[j];
      alo += w0 * bflo(p0); ahi += w0 * bfhi(p0);
    }
  }
  out[(size_t)row * rowU + uoff] = pack2(alpha * alo, alpha * ahi);
}

// ---------------- dual-direction propagate ----------------
__launch_bounds__(256)
__global__ void propagate_dual(const unsigned int* __restrict__ in,
                               unsigned int* __restrict__ outF, unsigned int* __restrict__ outB,
                               const int* __restrict__ rp_f, const int* __restrict__ col_f,
                               const float* __restrict__ wf,
                               const int* __restrict__ rp_b, const int* __restrict__ col_b,
                               const float* __restrict__ wb, int rowU) {
  __shared__ int scol[256];
  __shared__ float sw[256];
  int row = blockIdx.x % Nn;
  int chunk = blockIdx.x / Nn;
  int t = threadIdx.x;
  int uoff = chunk * 256 + t;
  {
    float alo = 0.f, ahi = 0.f;
    int jb = rp_f[row], je = rp_f[row + 1];
    for (int base = jb; base < je; base += 256) {
      int m = je - base; if (m > 256) m = 256;
      __syncthreads();
      if (t < m) { scol[t] = col_f[base + t]; sw[t] = wf[base + t]; }
      __syncthreads();
      int j = 0;
      for (; j + 4 <= m; j += 4) {
        unsigned int p0 = in[(size_t)scol[j + 0] * rowU + uoff];
        unsigned int p1 = in[(size_t)scol[j + 1] * rowU + uoff];
        unsigned int p2 = in[(size_t)scol[j + 2] * rowU + uoff];
        unsigned int p3 = in[(size_t)scol[j + 3] * rowU + uoff];
        float w0 = sw[j + 0], w1 = sw[j + 1], w2 = sw[j + 2], w3 = sw[j + 3];
        alo += w0 * bflo(p0); ahi += w0 * bfhi(p0);
        alo += w1 * bflo(p1); ahi += w1 * bfhi(p1);
        alo += w2 * bflo(p2); ahi += w2 * bfhi(p2);
        alo += w3 * bflo(p3); ahi += w3 * bfhi(p3);
      }
      for (; j < m; ++j) {
        unsigned int p0 = in[(size_t)scol[j] * rowU + uoff];
        float w0 = sw[j];
        alo += w0 * bflo(p0); ahi += w0 * bfhi(p0);
      }
    }
    outF[(size_t)row * rowU + uoff] = pack2(alo, ahi);
  }
  {
    float alo = 0.f, ahi = 0.f;
    int jb = rp_b[row], je = rp_b[row + 1];
    for (int base = jb; base < je; base += 256) {
      int m = je - base; if (m > 256) m = 256;
      __syncthreads();
      if (t < m) { scol[t] = col_b[base + t]; sw[t] = wb[base + t]; }
      __syncthreads();
      int j = 0;
      for (; j + 4 <= m; j += 4) {
        unsigned int p0 = in[(size_t)scol[j + 0] * rowU + uoff];
        unsigned int p1 = in[(size_t)scol[j + 1] * rowU + uoff];
        unsigned int p2 = in[(size_t)scol[j + 2] * rowU + uoff];
        unsigned int p3 = in[(size_t)scol[j + 3] * rowU + uoff];
        float w0 = sw[j + 0], w1 = sw[j + 1], w2 = sw[j + 2], w3 = sw[j + 3];
        alo += w0 * bflo(p0); ahi += w0 * bfhi(p0);
        alo += w1 * bflo(p1); ahi += w1 * bfhi(p1);
        alo += w2 * bflo(p2); ahi += w2 * bfhi(p2);
        alo += w3 * bflo(p3); ahi += w3 * bfhi(p3);
      }
      for (; j < m; ++j) {
        unsigned int p0 = in[(size_t)scol[j] * rowU + uoff];
        float w0 = sw[j];
        alo += w0 * bflo(p0); ahi += w0 * bfhi(p0);
      }
    }
    outB[(size_t)row * rowU + uoff] = pack2(alo, ahi);
  }
}

// ---------------- MFMA multi-term GEMM ----------------
// C[128 x NT] per block; 4 waves, each 32 x NT. K = nterms*96.
// Weight columns for loop term t are taken at (t0 + t)*96  <-- t0 fixes the round-5 bug.
// A term source: full (rh==null): contiguous bf16 rows (12 uint4/row);
//                split: x-part (4 uint4) from full-width buffer + rh-part (8 uint4) compact.
// MFMA layouts (verified): A[m=lane&15][k=quad*8+j]; B[k=quad*8+j][n=lane&15];
//                          C/D col=lane&15, row=quad*4+reg.
// MODE 0: conv1 epilogue: v=sigmoid(bias+acc); col<64 -> rh0=v*h (bf16); else U=v (bf16)
// MODE 1: outp = bias + acc (f32, batch-major)
// MODE 2: cp = outp + acc; c=tanh(tanh(cp)); u from U_in; outp = u*h + (1-u)*c
struct Msrc {
  const uint4* xs[5];
  const uint4* rh[5];
};

template<int NT, int MODE>
__launch_bounds__(256)
__global__ void gemm_mfma(Msrc g, int nterms, int t0,
                          const unsigned short* __restrict__ Wt,
                          const float* __restrict__ bias,
                          float* __restrict__ outp,
                          unsigned short* __restrict__ rh0_s,
                          unsigned short* __restrict__ U_out,
                          const unsigned short* __restrict__ U_in,
                          const float* __restrict__ hglob) {
  constexpr int NJ = NT / 16;
  __shared__ __align__(16) unsigned short As[128][104];   // 13 x 16B per row (odd -> conflict-free)
  __shared__ __align__(16) unsigned short Bs[NT][104];

  int m0 = blockIdx.x * 128;
  int tid = threadIdx.x;
  int wave = tid >> 6;
  int lane = tid & 63;
  int quad = lane >> 4;
  int lm = lane & 15;
  int wm = wave * 32;
  int nodeBase = m0 >> 4;

  f32x4 acc[2][NJ];
  #pragma unroll
  for (int i = 0; i < 2; ++i)
    #pragma unroll
    for (int j = 0; j < NJ; ++j) acc[i][j] = (f32x4){0.f, 0.f, 0.f, 0.f};

  for (int t = 0; t < nterms; ++t) {
    const uint4* xs4 = g.xs[t];
    const uint4* rh4 = g.rh[t];
    if (rh4 == nullptr) {
      const uint4* src = xs4 + (size_t)m0 * 12;
      #pragma unroll
      for (int it = 0; it < 6; ++it) {
        int q = tid + it * 256;
        uint4 v = src[q];
        int row = q / 12, slot = q % 12;
        *(uint4*)&As[row][slot * 8] = v;
      }
    } else {
      #pragma unroll
      for (int it = 0; it < 6; ++it) {
        int q = tid + it * 256;
        int row = q / 12, slot = q % 12;
        int node = nodeBase + (row >> 4);
        int b = row & 15;
        uint4 v; int ci0;
        if (slot < 4) { v = xs4[(size_t)node * 192 + b * 12 + slot]; ci0 = slot * 8; }
        else          { v = rh4[(size_t)node * 128 + b * 8 + (slot - 4)]; ci0 = 32 + (slot - 4) * 8; }
        *(uint4*)&As[row][ci0] = v;
      }
    }
    for (int q = tid; q < NT * 12; q += 256) {
      int n = q / 12, slot = q % 12;
      uint4 v = *(const uint4*)(Wt + (size_t)n * 480 + (t0 + t) * 96 + slot * 8);
      *(uint4*)&Bs[n][slot * 8] = v;
    }
    __syncthreads();

    #pragma unroll
    for (int k32 = 0; k32 < 3; ++k32) {
      int kb = k32 * 32 + quad * 8;
      short8 a0 = *(const short8*)&As[wm + lm][kb];
      short8 a1 = *(const short8*)&As[wm + 16 + lm][kb];
      #pragma unroll
      for (int j = 0; j < NJ; ++j) {
        short8 bf = *(const short8*)&Bs[j * 16 + lm][kb];
        acc[0][j] = __builtin_amdgcn_mfma_f32_16x16x32_bf16(a0, bf, acc[0][j], 0, 0, 0);
        acc[1][j] = __builtin_amdgcn_mfma_f32_16x16x32_bf16(a1, bf, acc[1][j], 0, 0, 0);
      }
    }
    __syncthreads();
  }

  #pragma unroll
  for (int i = 0; i < 2; ++i) {
    #pragma unroll
    for (int j = 0; j < NJ; ++j) {
      int col = j * 16 + lm;
      #pragma unroll
      for (int r = 0; r < 4; ++r) {
        int row = m0 + wm + i * 16 + quad * 4 + r;
        int node = row >> 4, b = row & 15;
        float v = acc[i][j][r];
        if (MODE == 0) {
          float s = 1.f / (1.f + expf(-(bias[col] + v)));
          if (col < COUTn) {
            float hv = hglob[((size_t)b * Nn + node) * COUTn + col];
            rh0_s[(size_t)row * 64 + col] = (unsigned short)f2bfbits(s * hv);
          } else {
            U_out[(size_t)row * 64 + (col - COUTn)] = (unsigned short)f2bfbits(s);
          }
        } else if (MODE == 1) {
          outp[((size_t)b * Nn + node) * COUTn + col] = bias[col] + v;
        } else {
          size_t oa = ((size_t)b * Nn + node) * COUTn + col;
          float cp = outp[oa] + v;
          float c = tanhf(tanhf(cp));
          float u = bf2f(U_in[(size_t)row * 64 + col]);
          outp[oa] = u * hglob[oa] + (1.f - u) * c;
        }
      }
    }
  }
}

// ---------------- host ----------------
extern "C" void kernel_launch(void* const* d_in, const int* in_sizes, int n_in,
                              void* d_out, int out_size, void* d_ws, size_t ws_size,
                              hipStream_t stream) {
  const float* x   = (const float*)d_in[0];
  const float* h   = (const float*)d_in[1];
  const int*   idx = (const int*)d_in[2];
  const float* ew  = (const float*)d_in[3];
  const float* ru_param = (const float*)d_in[4];
  const float* ru_bias  = (const float*)d_in[5];
  const float* c_param  = (const float*)d_in[6];
  const float* c_bias   = (const float*)d_in[7];
  float* outp = (float*)d_out;
  (void)in_sizes; (void)n_in; (void)out_size; (void)ws_size;

  char* ws = (char*)d_ws;
  size_t off = 0;
  auto alloc = [&](size_t bytes) -> char* {
    char* p = ws + off;
    off += (bytes + 255) & ~(size_t)255;
    return p;
  };

  float* deg_f = (float*)alloc(40960);
  float* deg_b = (float*)alloc(40960);
  int*   cnt_f = (int*)alloc(40960);
  int*   cnt_b = (int*)alloc(40960);
  int*   rp_f  = (int*)alloc((Nn + 1) * sizeof(int));
  int*   rp_b  = (int*)alloc((Nn + 1) * sizeof(int));
  int*   cur_f = (int*)alloc(Nn * sizeof(int));
  int*   cur_b = (int*)alloc(Nn * sizeof(int));
  int*   flag  = (int*)alloc(256);
  int*   col_f = (int*)alloc(En * sizeof(int));
  float* wf    = (float*)alloc(En * sizeof(float));
  int*   col_b = (int*)alloc(En * sizeof(int));
  float* wb    = (float*)alloc(En * sizeof(float));
  unsigned short* Wt1 = (unsigned short*)alloc(128 * 480 * 2);
  unsigned short* Wt2 = (unsigned short*)alloc(64 * 480 * 2);

  unsigned int* A0   = (unsigned int*)alloc((size_t)Nn * WROWU * 4);
  unsigned int* T1f  = (unsigned int*)alloc((size_t)Nn * WROWU * 4);
  unsigned int* T1b  = (unsigned int*)alloc((size_t)Nn * WROWU * 4);
  unsigned int* T2f  = (unsigned int*)alloc((size_t)Nn * WROWU * 4);
  unsigned int* T2b  = (unsigned int*)alloc((size_t)Nn * WROWU * 4);
  unsigned int* rh0  = (unsigned int*)alloc((size_t)Nn * RHU * 4);
  unsigned int* rh1f = (unsigned int*)alloc((size_t)Nn * RHU * 4);
  unsigned int* rh1b = (unsigned int*)alloc((size_t)Nn * RHU * 4);
  unsigned int* Ubuf = (unsigned int*)alloc((size_t)Nn * RHU * 4);
  // ~241 MB total

  hipMemsetAsync(ws, 0, 4 * 40960, stream);
  detect_idx<<<1, 64, 0, stream>>>(idx, flag);
  deg_cnt_kernel<<<En / 256, 256, 0, stream>>>(idx, ew, deg_f, deg_b, cnt_f, cnt_b, flag);
  exscan_two<<<2, 256, 0, stream>>>(cnt_f, cnt_b, rp_f, rp_b, cur_f, cur_b, Nn);
  fill_csr<<<En / 256, 256, 0, stream>>>(idx, ew, deg_f, deg_b, cur_f, cur_b,
                                         col_f, wf, col_b, wb, flag);
  build_wt<<<240, 256, 0, stream>>>(ru_param, c_param, Wt1, Wt2);

  const int gBuild = Nn * WROWU / 256;

  // ===== conv1 diffusion =====
  build_x0_ru<<<gBuild, 256, 0, stream>>>(x, h, A0);
  propagate_dual<<<3 * Nn, 256, 0, stream>>>(A0, T1f, T1b, rp_f, col_f, wf,
                                             rp_b, col_b, wb, WROWU);
  propagate_ck<<<3 * Nn, 256, 0, stream>>>(T1f, T2f, rp_f, col_f, wf, 2.f, WROWU);
  propagate_ck<<<3 * Nn, 256, 0, stream>>>(T1b, T2b, rp_b, col_b, wb, 2.f, WROWU);

  // ===== conv1 projection: one MFMA GEMM K=480, fused sigmoid + r*h + u-store =====
  Msrc g1;
  g1.xs[0] = (const uint4*)A0;  g1.rh[0] = nullptr;
  g1.xs[1] = (const uint4*)T1f; g1.rh[1] = nullptr;
  g1.xs[2] = (const uint4*)T1b; g1.rh[2] = nullptr;
  g1.xs[3] = (const uint4*)T2f; g1.rh[3] = nullptr;
  g1.xs[4] = (const uint4*)T2b; g1.rh[4] = nullptr;
  gemm_mfma<128, 0><<<MROWS / 128, 256, 0, stream>>>(
      g1, 5, 0, Wt1, ru_bias, nullptr,
      (unsigned short*)rh0, (unsigned short*)Ubuf, nullptr, h);

  // ===== conv2 diffusion on rh =====
  propagate_dual<<<2 * Nn, 256, 0, stream>>>(rh0, rh1f, rh1b, rp_f, col_f, wf,
                                             rp_b, col_b, wb, RHU);

  // conv2 pass A: terms 0,1,2 (weight base t0=0)
  Msrc g2a;
  g2a.xs[0] = (const uint4*)A0;  g2a.rh[0] = (const uint4*)rh0;
  g2a.xs[1] = (const uint4*)T1f; g2a.rh[1] = (const uint4*)rh1f;
  g2a.xs[2] = (const uint4*)T1b; g2a.rh[2] = (const uint4*)rh1b;
  g2a.xs[3] = nullptr; g2a.rh[3] = nullptr;
  g2a.xs[4] = nullptr; g2a.rh[4] = nullptr;
  gemm_mfma<64, 1><<<MROWS / 128, 256, 0, stream>>>(
      g2a, 3, 0, Wt2, c_bias, outp, nullptr, nullptr, nullptr, nullptr);

  // rh second-order terms (reuse rh0/rh1f storage after pass A consumed them)
  propagate_ck<<<2 * Nn, 256, 0, stream>>>(rh1f, rh0, rp_f, col_f, wf, 2.f, RHU);   // rh2f
  propagate_ck<<<2 * Nn, 256, 0, stream>>>(rh1b, rh1f, rp_b, col_b, wb, 2.f, RHU);  // rh2b

  // conv2 pass B: terms 3,4 (weight base t0=3) + fused GRU final
  Msrc g2b;
  g2b.xs[0] = (const uint4*)T2f; g2b.rh[0] = (const uint4*)rh0;
  g2b.xs[1] = (const uint4*)T2b; g2b.rh[1] = (const uint4*)rh1f;
  g2b.xs[2] = nullptr; g2b.rh[2] = nullptr;
  g2b.xs[3] = nullptr; g2b.rh[3] = nullptr;
  g2b.xs[4] = nullptr; g2b.rh[4] = nullptr;
  gemm_mfma<64, 2><<<MROWS / 128, 256, 0, stream>>>(
      g2b, 2, 3, Wt2, c_bias, outp, nullptr, nullptr,
      (const unsigned short*)Ubuf, h);
}